// Round 10
// baseline (241.562 us; speedup 1.0000x reference)
//
#include <hip/hip_runtime.h>
#include <hip/hip_bf16.h>
#include <math.h>

// Problem constants
#define BS 32
#define SEQ 50
#define ML 16
#define NN 15
#define NTREE (BS*SEQ*ML)     // 25600
#define NROW (BS*SEQ)         // 1600
#define VOCAB 50000
#define EMB 128
#define ENC 128
#define GH 32
#define NC 100
#define LH 128
#define LIN_D 167             // 101 + 64 + 2
#define LIN_P 192             // padded K for the xeL GEMM (vector path)

typedef float f32x4 __attribute__((ext_vector_type(4)));
typedef unsigned int u32;
typedef u32 u32x4 __attribute__((ext_vector_type(4)));

// ---------------------------------------------------------------------------
// fp32 GEMM: C[M][N] = A[M][K] @ B[N][K]^T (+ bias[N])
// BM=64 x BN=128 tile, BK=32, 256 threads, 4x8 per thread.
// ---------------------------------------------------------------------------
__global__ __launch_bounds__(256) void sgemm_nt(const float* __restrict__ A,
    const float* __restrict__ B, const float* __restrict__ bias,
    float* __restrict__ C, int M, int N, int K) {
  __shared__ float As[32][68];    // [k][m]
  __shared__ float Bs[32][132];   // [k][n]
  const int bm = blockIdx.y * 64, bn = blockIdx.x * 128;
  const int tid = threadIdx.x;
  const int tm = (tid >> 4) << 2;   // 0..60
  const int tn = (tid & 15) << 3;   // 0..120
  const int srow = tid >> 3;        // 0..31
  const int q4 = (tid & 7) << 2;    // 0,4,..,28
  const bool vec_ok = ((K & 3) == 0);

  float acc[4][8];
  #pragma unroll
  for (int i = 0; i < 4; i++)
    #pragma unroll
    for (int j = 0; j < 8; j++) acc[i][j] = 0.f;

  for (int k0 = 0; k0 < K; k0 += 32) {
    if (vec_ok && (k0 + 32 <= K)) {
      #pragma unroll
      for (int h = 0; h < 2; h++) {
        int gm = bm + srow + h * 32;
        int rm = (gm < M) ? gm : (M - 1);
        float4 av = *(const float4*)&A[(size_t)rm * K + k0 + q4];
        As[q4 + 0][srow + h * 32] = av.x;
        As[q4 + 1][srow + h * 32] = av.y;
        As[q4 + 2][srow + h * 32] = av.z;
        As[q4 + 3][srow + h * 32] = av.w;
      }
      #pragma unroll
      for (int h = 0; h < 4; h++) {
        int gn = bn + srow + h * 32;
        float4 bv = make_float4(0.f, 0.f, 0.f, 0.f);
        if (gn < N) bv = *(const float4*)&B[(size_t)gn * K + k0 + q4];
        Bs[q4 + 0][srow + h * 32] = bv.x;
        Bs[q4 + 1][srow + h * 32] = bv.y;
        Bs[q4 + 2][srow + h * 32] = bv.z;
        Bs[q4 + 3][srow + h * 32] = bv.w;
      }
    } else {
      #pragma unroll
      for (int h = 0; h < 2; h++) {
        int gm = bm + srow + h * 32;
        int rm = (gm < M) ? gm : (M - 1);
        #pragma unroll
        for (int j = 0; j < 4; j++) {
          int gk = k0 + q4 + j;
          As[q4 + j][srow + h * 32] = (gk < K) ? A[(size_t)rm * K + gk] : 0.f;
        }
      }
      #pragma unroll
      for (int h = 0; h < 4; h++) {
        int gn = bn + srow + h * 32;
        #pragma unroll
        for (int j = 0; j < 4; j++) {
          int gk = k0 + q4 + j;
          Bs[q4 + j][srow + h * 32] =
              (gn < N && gk < K) ? B[(size_t)gn * K + gk] : 0.f;
        }
      }
    }
    __syncthreads();
    #pragma unroll
    for (int kk = 0; kk < 32; kk++) {
      float4 a4 = *(const float4*)&As[kk][tm];
      float4 b0 = *(const float4*)&Bs[kk][tn];
      float4 b1 = *(const float4*)&Bs[kk][tn + 4];
      float a[4] = {a4.x, a4.y, a4.z, a4.w};
      float b[8] = {b0.x, b0.y, b0.z, b0.w, b1.x, b1.y, b1.z, b1.w};
      #pragma unroll
      for (int i = 0; i < 4; i++)
        #pragma unroll
        for (int j = 0; j < 8; j++) acc[i][j] += a[i] * b[j];
    }
    __syncthreads();
  }

  float bb[8];
  #pragma unroll
  for (int j = 0; j < 8; j++) {
    int gn = bn + tn + j;
    bb[j] = (bias && gn < N) ? bias[gn] : 0.f;
  }
  if (bn + tn < N) {
    #pragma unroll
    for (int i = 0; i < 4; i++) {
      int gm = bm + tm + i;
      if (gm >= M) continue;
      float4 v0 = make_float4(acc[i][0] + bb[0], acc[i][1] + bb[1],
                              acc[i][2] + bb[2], acc[i][3] + bb[3]);
      float4 v1 = make_float4(acc[i][4] + bb[4], acc[i][5] + bb[5],
                              acc[i][6] + bb[6], acc[i][7] + bb[7]);
      *(float4*)&C[(size_t)gm * N + bn + tn] = v0;
      *(float4*)&C[(size_t)gm * N + bn + tn + 4] = v1;
    }
  }
}

// ---------------------------------------------------------------------------
// Prep: Wall = [WxF; WxB] (192x128), ball = [bxF; bxB],
//       Wxp = lstm_Wx zero-padded K 167 -> 192 (512 x 192),
//       Whb = lstm_Wh packed as bf16 pairs (512 x 64 u32, RNE rounding)
// ---------------------------------------------------------------------------
__global__ __launch_bounds__(256) void k_prep(const float* __restrict__ WxF,
    const float* __restrict__ WxB, const float* __restrict__ bxF,
    const float* __restrict__ bxB, const float* __restrict__ lstm_Wx,
    const float* __restrict__ lstm_Wh,
    float* __restrict__ Wall, float* __restrict__ ball,
    float* __restrict__ Wxp, u32* __restrict__ Whb) {
  int i = blockIdx.x * 256 + threadIdx.x;
  if (i < 96 * 128) Wall[i] = WxF[i];
  else if (i < 192 * 128) Wall[i] = WxB[i - 96 * 128];
  if (i < 96) ball[i] = bxF[i];
  else if (i < 192) ball[i] = bxB[i - 96];
  if (i < 512 * LIN_P) {
    int n = i / LIN_P, k = i - n * LIN_P;
    Wxp[i] = (k < LIN_D) ? lstm_Wx[n * LIN_D + k] : 0.f;
  }
  if (i < 512 * 64) {
    int g = i >> 6, j = i & 63;
    u32 a = __float_as_uint(lstm_Wh[g * 128 + 2 * j]);
    u32 bb = __float_as_uint(lstm_Wh[g * 128 + 2 * j + 1]);
    a  = (a  + 0x7FFFu + ((a  >> 16) & 1u)) >> 16;
    bb = (bb + 0x7FFFu + ((bb >> 16) & 1u)) >> 16;
    Whb[i] = a | (bb << 16);
  }
}

// ---------------------------------------------------------------------------
// Tree: gather 15 rows of E', bottom-up subtree sums, node max. 2 trees/block.
// ---------------------------------------------------------------------------
__global__ __launch_bounds__(256) void k_tree(const int* __restrict__ ast,
    const float* __restrict__ Ep, const float* __restrict__ Wc_b,
    float* __restrict__ x) {
  int lt = threadIdx.x >> 7;      // 0/1
  int d  = threadIdx.x & 127;
  int tree = blockIdx.x * 2 + lt;
  __shared__ int toks[2][15];
  if (d < 15) toks[lt][d] = ast[(size_t)tree * 15 + d];
  __syncthreads();
  float e[15];
  #pragma unroll
  for (int n = 0; n < 15; n++) e[n] = Ep[(size_t)toks[lt][n] * 128 + d];
  float b = Wc_b[d];
  float s3 = e[3] + e[7] + e[8],  s4 = e[4] + e[9] + e[10];
  float s5 = e[5] + e[11] + e[12], s6 = e[6] + e[13] + e[14];
  float s1 = e[1] + s3 + s4, s2 = e[2] + s5 + s6;
  float s0 = e[0] + s1 + s2;
  float ml = fmaxf(fmaxf(fmaxf(e[7], e[8]), fmaxf(e[9], e[10])),
                   fmaxf(fmaxf(e[11], e[12]), fmaxf(e[13], e[14]))) + b;
  float mm = fmaxf(fmaxf(s3, s4), fmaxf(s5, s6)) + 3.f * b;
  float mt = fmaxf(s1, s2) + 7.f * b;
  float m = fmaxf(fmaxf(ml, mm), fmaxf(mt, s0 + 15.f * b));
  x[(size_t)tree * 128 + d] = m;
}

// ---------------------------------------------------------------------------
// GRU recurrence, one block per (sequence, direction). Hidden=32, gates=96.
// ---------------------------------------------------------------------------
__global__ __launch_bounds__(128) void k_gru(const float* __restrict__ xe_all,
    const float* __restrict__ WhF, const float* __restrict__ WhB,
    const float* __restrict__ bhF, const float* __restrict__ bhB,
    float* __restrict__ code) {
  int bsq = blockIdx.x >> 1, dir = blockIdx.x & 1;
  int g = threadIdx.x;
  __shared__ float whs[96 * 32];
  __shared__ float h_lds[32];
  __shared__ float rz[64];
  __shared__ float nn[32];
  const float* Wh = dir ? WhB : WhF;
  const float* bh = dir ? bhB : bhF;
  for (int i = g; i < 96 * 32; i += 128) whs[i] = Wh[i];
  if (g < 32) h_lds[g] = 0.f;
  __syncthreads();
  float w[32]; float bhv = 0.f, mxv = -1e30f;
  if (g < 96) {
    #pragma unroll
    for (int j = 0; j < 32; j++) w[j] = whs[g * 32 + j];
    bhv = bh[g];
  }
  for (int s = 0; s < 16; s++) {
    int t = dir ? (15 - s) : s;
    const float* xe = xe_all + ((size_t)(bsq * 16 + t)) * 192 + dir * 96;
    float gh = bhv, xv = 0.f;
    if (g < 96) {
      xv = xe[g];
      #pragma unroll
      for (int j = 0; j < 32; j++) gh += w[j] * h_lds[j];
    }
    if (g < 64) rz[g] = 1.f / (1.f + expf(-(xv + gh)));
    __syncthreads();
    if (g >= 64 && g < 96) nn[g - 64] = tanhf(xv + rz[g - 64] * gh);
    __syncthreads();
    if (g < 32) {
      float z = rz[g + 32];
      float hn = (1.f - z) * nn[g] + z * h_lds[g];
      mxv = fmaxf(mxv, hn);
      h_lds[g] = hn;
    }
    __syncthreads();
  }
  if (g < 32) code[(size_t)bsq * 64 + dir * 32 + g] = mxv;
}

// ---------------------------------------------------------------------------
// Build lin = [c_embed(101) | code(64) | cur_result(2) | 0-pad to 192]
// ---------------------------------------------------------------------------
__global__ __launch_bounds__(256) void k_lin(const float* __restrict__ c_embed,
    const float* __restrict__ code, const float* __restrict__ cur,
    float* __restrict__ lin) {
  int i = blockIdx.x * 256 + threadIdx.x;
  if (i >= NROW * LIN_P) return;
  int row = i / LIN_P, j = i - row * LIN_P;
  float v;
  if (j < 101) v = c_embed[row * 101 + j];
  else if (j < 165) v = code[row * 64 + (j - 101)];
  else if (j < 167) v = cur[row * 2 + (j - 165)];
  else v = 0.f;
  lin[i] = v;
}

// ---------------------------------------------------------------------------
// LSTM v9: weights in LDS as bf16 pairs — residency GUARANTEED (no register
// allocator involvement; R2-R8 all spilled regardless of structure).
// 32 blocks x 512 threads, 1 block/CU (133 KB LDS). Thread t owns gate row t:
// 64 u32 (2xbf16) in LDS, XOR-16B swizzled so the 16 ds_read_b128/step hit
// all 32 banks (8-cyc floor). Unpack bf16 = shl/and (no cvt). h broadcast
// via v_readlane. No libm. ~410 VALU + 19 LDS instr/thread/step.
// ---------------------------------------------------------------------------
#define RL(v, l) __int_as_float(__builtin_amdgcn_readlane(__float_as_int(v), (l)))
#define LOG2E 1.4426950408889634f

__device__ __forceinline__ float fsig(float x) {
  return __builtin_amdgcn_rcpf(1.f + __builtin_amdgcn_exp2f(-LOG2E * x));
}
__device__ __forceinline__ float ftanh(float x) {
  return 2.f * __builtin_amdgcn_rcpf(
             1.f + __builtin_amdgcn_exp2f(-2.f * LOG2E * x)) - 1.f;
}

__global__ __attribute__((amdgpu_flat_work_group_size(512, 512)))
void k_lstm(const float* __restrict__ xeL, const u32* __restrict__ Whb,
            const float* __restrict__ bh, float* __restrict__ lout) {
  __shared__ u32x4 Wl[512 * 16];   // 131072 B, swizzled bf16 weight pairs
  __shared__ float hbuf[128];
  __shared__ float ga[512];
  int b = blockIdx.x; int t = threadIdx.x;
  int lane = t & 63;
  // stage weights: coalesced global read, swizzled LDS write (once)
  const u32x4* Wg = (const u32x4*)Whb;
  #pragma unroll
  for (int j = 0; j < 16; j++) {
    int g = t + j * 512;            // 0..8191
    u32x4 v = Wg[g];
    int r = g >> 4, cc = g & 15;
    Wl[(r << 4) + (cc ^ (r & 7))] = v;
  }
  float bhv = bh[t];
  float c = 0.f;
  const bool is_tanh_gate = ((t >> 7) == 2);   // gates 256..383 = g-gate
  if (t < 128) hbuf[t] = 0.f;
  const float* xrow = xeL + (size_t)b * 50 * 512;
  float xe = xrow[t];                 // step-0 prefetch
  const int IB = (t << 4) + (t & 7);  // swizzled row base (u32x4 units)
  __syncthreads();
  for (int step = 0; step < 50; step++) {
    float h0 = hbuf[lane];
    float h1 = hbuf[64 + lane];
    float acc_a = xe + bhv, acc_b = 0.f;
    if (step < 49) xe = xrow[(size_t)(step + 1) * 512 + t];
    u32x4 p;
#define MACQ(Q, H, L0, L1) { \
    float we = __int_as_float((int)((Q) << 16)); \
    float wo = __int_as_float((int)((Q) & 0xFFFF0000u)); \
    acc_a += we * RL(H, L0); \
    acc_b += wo * RL(H, L1); }
#define CHUNK(I, H, K) \
    p = Wl[IB ^ I]; \
    MACQ(p[0], H, (K)+0, (K)+1) MACQ(p[1], H, (K)+2, (K)+3) \
    MACQ(p[2], H, (K)+4, (K)+5) MACQ(p[3], H, (K)+6, (K)+7)
    CHUNK(0,  h0, 0)  CHUNK(1,  h0, 8)  CHUNK(2,  h0, 16) CHUNK(3,  h0, 24)
    CHUNK(4,  h0, 32) CHUNK(5,  h0, 40) CHUNK(6,  h0, 48) CHUNK(7,  h0, 56)
    CHUNK(8,  h1, 0)  CHUNK(9,  h1, 8)  CHUNK(10, h1, 16) CHUNK(11, h1, 24)
    CHUNK(12, h1, 32) CHUNK(13, h1, 40) CHUNK(14, h1, 48) CHUNK(15, h1, 56)
#undef CHUNK
#undef MACQ
    float gav = acc_a + acc_b;
    ga[t] = is_tanh_gate ? ftanh(gav) : fsig(gav);
    __syncthreads();
    if (t < 128) {
      c = ga[t + 128] * c + ga[t] * ga[t + 256];
      float h = ga[t + 384] * ftanh(c);
      hbuf[t] = h;
      lout[((size_t)b * 50 + step) * 128 + t] = h;
    }
    __syncthreads();
  }
}

// ---------------------------------------------------------------------------
// Prediction head: p1 = lout . (pred_w^T tc) + tc . pred_b
// ---------------------------------------------------------------------------
__global__ __launch_bounds__(128) void k_pred(const float* __restrict__ lout,
    const float* __restrict__ pred_w, const float* __restrict__ pred_b,
    const float* __restrict__ tc, const float* __restrict__ result,
    float* __restrict__ out, float* __restrict__ fpbuf, float* __restrict__ mbuf) {
  int row = blockIdx.x; int k = threadIdx.x;
  __shared__ float tcs[101];
  __shared__ float r1[128], r2[128], r3[128];
  if (k < 101) tcs[k] = tc[(size_t)row * 101 + k];
  __syncthreads();
  float lk = lout[(size_t)row * 128 + k];
  float acc = 0.f;
  for (int c = 0; c < 101; c++) acc += tcs[c] * pred_w[c * 128 + k];
  float v = acc * lk;
  float pb = (k < 101) ? tcs[k] * pred_b[k] : 0.f;
  float nc = (k < 101) ? tcs[k] : 0.f;
  r1[k] = v; r2[k] = pb; r3[k] = nc;
  __syncthreads();
  for (int st = 64; st > 0; st >>= 1) {
    if (k < st) { r1[k] += r1[k + st]; r2[k] += r2[k + st]; r3[k] += r3[k + st]; }
    __syncthreads();
  }
  if (k == 0) {
    float ncon = r3[0];
    float m = (ncon > 0.f) ? 1.f : 0.f;
    float fp = (r1[0] + r2[0]) / fmaxf(ncon, 1.f);
    fpbuf[row] = fp; mbuf[row] = m;
    out[1 + row] = m / (1.f + expf(-fp));
    out[1 + NROW + row] = result[row] * m;
  }
}

// ---------------------------------------------------------------------------
// Loss reduction (single block, deterministic tree reduce)
// ---------------------------------------------------------------------------
__global__ __launch_bounds__(256) void k_loss(const float* __restrict__ fpbuf,
    const float* __restrict__ mbuf, const float* __restrict__ result,
    float* __restrict__ out) {
  __shared__ float sb[256], sm[256];
  int k = threadIdx.x;
  float ab = 0.f, am = 0.f;
  for (int r = k; r < NROW; r += 256) {
    float fp = fpbuf[r], m = mbuf[r], res = result[r];
    float bce = fmaxf(fp, 0.f) - fp * res + log1pf(expf(-fabsf(fp)));
    ab += bce * m; am += m;
  }
  sb[k] = ab; sm[k] = am;
  __syncthreads();
  for (int st = 128; st > 0; st >>= 1) {
    if (k < st) { sb[k] += sb[k + st]; sm[k] += sm[k + st]; }
    __syncthreads();
  }
  if (k == 0) out[0] = sb[0] / fmaxf(sm[0], 1.f);
}

// ---------------------------------------------------------------------------
extern "C" void kernel_launch(void* const* d_in, const int* in_sizes, int n_in,
                              void* d_out, int out_size, void* d_ws, size_t ws_size,
                              hipStream_t stream) {
  (void)in_sizes; (void)n_in; (void)out_size; (void)ws_size;
  const int*   ast      = (const int*)  d_in[2];
  const float* target_c = (const float*)d_in[3];
  const float* c_embed  = (const float*)d_in[4];
  const float* cur_res  = (const float*)d_in[5];
  const float* result   = (const float*)d_in[6];
  const float* emb      = (const float*)d_in[7];
  const float* Wc_w     = (const float*)d_in[8];
  const float* Wc_b     = (const float*)d_in[9];
  const float* gru_WxF  = (const float*)d_in[10];
  const float* gru_WhF  = (const float*)d_in[11];
  const float* gru_bxF  = (const float*)d_in[12];
  const float* gru_bhF  = (const float*)d_in[13];
  const float* gru_WxB  = (const float*)d_in[14];
  const float* gru_WhB  = (const float*)d_in[15];
  const float* gru_bxB  = (const float*)d_in[16];
  const float* gru_bhB  = (const float*)d_in[17];
  const float* lstm_Wx  = (const float*)d_in[18];
  const float* lstm_Wh  = (const float*)d_in[19];
  const float* lstm_bx  = (const float*)d_in[20];
  const float* lstm_bh  = (const float*)d_in[21];
  const float* pred_w   = (const float*)d_in[22];
  const float* pred_b   = (const float*)d_in[23];
  float* out = (float*)d_out;

  float* W = (float*)d_ws;
  float* Ep     = W;                 // 6,400,000 (VOCAB*128)
  float* xe_all = W;                 // alias: 25600*192 = 4,915,200 <= Ep size
  float* x      = W + 6400000;       // 3,276,800
  float* Wall   = W + 9676800;       // 24,576
  float* ball   = W + 9701376;       // 192
  float* Wxp    = W + 9701568;       // 98,304 (512 x 192)
  float* code   = W + 9799872;       // 102,400
  float* lin    = W + 9902272;       // 307,200 (1600 x 192)
  float* xeL    = W + 10209472;      // 819,200
  float* lout   = W + 11028672;      // 204,800
  float* fpbuf  = W + 11233472;      // 1,600
  float* mbuf   = W + 11235072;      // 1,600
  u32*   Whb    = (u32*)(W + 11236672); // 32,768 u32 (512 x 64 bf16 pairs)

  // 1. E' = emb @ Wc_w^T   (vocab-level projection)
  sgemm_nt<<<dim3(1, 782), 256, 0, stream>>>(emb, Wc_w, nullptr, Ep, VOCAB, 128, 128);
  // 2. weight prep (Wx pad 167->192, Wh -> bf16 pairs)
  k_prep<<<384, 256, 0, stream>>>(gru_WxF, gru_WxB, gru_bxF, gru_bxB, lstm_Wx,
                                  lstm_Wh, Wall, ball, Wxp, Whb);
  // 3. tree gather/sum/max -> x (25600 x 128)
  k_tree<<<NTREE / 2, 256, 0, stream>>>(ast, Ep, Wc_b, x);
  // 4. xe_all = x @ Wall^T + ball  (25600 x 192)  [aliases Ep region]
  sgemm_nt<<<dim3(2, 400), 256, 0, stream>>>(x, Wall, ball, xe_all, NTREE, 192, 128);
  // 5. GRU recurrence + time max -> code (1600 x 64)
  k_gru<<<NROW * 2, 128, 0, stream>>>(xe_all, gru_WhF, gru_WhB, gru_bhF, gru_bhB, code);
  // 6. lin build (1600 x 192, zero-padded)
  k_lin<<<(NROW * LIN_P + 255) / 256, 256, 0, stream>>>(c_embed, code, cur_res, lin);
  // 7. xeL = lin @ Wxp^T + lstm_bx (1600 x 512, K=192 vector path)
  sgemm_nt<<<dim3(4, 25), 256, 0, stream>>>(lin, Wxp, lstm_bx, xeL, NROW, 512, LIN_P);
  // 8. LSTM recurrence -> lout (1600 x 128)  [bf16 weights resident in LDS]
  k_lstm<<<BS, 512, 0, stream>>>(xeL, Whb, lstm_bh, lout);
  // 9. prediction head -> out[1..], fpbuf, mbuf
  k_pred<<<NROW, 128, 0, stream>>>(lout, pred_w, pred_b, target_c, result,
                                   out, fpbuf, mbuf);
  // 10. loss -> out[0]
  k_loss<<<1, 256, 0, stream>>>(fpbuf, mbuf, result, out);
}

// Round 11
// 208.295 us; speedup vs baseline: 1.1597x; 1.1597x over previous
//
#include <hip/hip_runtime.h>
#include <hip/hip_bf16.h>
#include <math.h>

// Problem constants
#define BS 32
#define SEQ 50
#define ML 16
#define NN 15
#define NTREE (BS*SEQ*ML)     // 25600
#define NROW (BS*SEQ)         // 1600
#define VOCAB 50000
#define EMB 128
#define ENC 128
#define GH 32
#define NC 100
#define LH 128
#define LIN_D 167             // 101 + 64 + 2
#define LIN_P 192             // padded K for the xeL GEMM (vector path)

typedef float f32x4 __attribute__((ext_vector_type(4)));
typedef short s16x8 __attribute__((ext_vector_type(8)));
typedef unsigned int u32;

// ---------------------------------------------------------------------------
// fp32 GEMM: C[M][N] = A[M][K] @ B[N][K]^T (+ bias[N])
// BM=64 x BN=128 tile, BK=32, 256 threads, 4x8 per thread.
// ---------------------------------------------------------------------------
__global__ __launch_bounds__(256) void sgemm_nt(const float* __restrict__ A,
    const float* __restrict__ B, const float* __restrict__ bias,
    float* __restrict__ C, int M, int N, int K) {
  __shared__ float As[32][68];    // [k][m]
  __shared__ float Bs[32][132];   // [k][n]
  const int bm = blockIdx.y * 64, bn = blockIdx.x * 128;
  const int tid = threadIdx.x;
  const int tm = (tid >> 4) << 2;   // 0..60
  const int tn = (tid & 15) << 3;   // 0..120
  const int srow = tid >> 3;        // 0..31
  const int q4 = (tid & 7) << 2;    // 0,4,..,28
  const bool vec_ok = ((K & 3) == 0);

  float acc[4][8];
  #pragma unroll
  for (int i = 0; i < 4; i++)
    #pragma unroll
    for (int j = 0; j < 8; j++) acc[i][j] = 0.f;

  for (int k0 = 0; k0 < K; k0 += 32) {
    if (vec_ok && (k0 + 32 <= K)) {
      #pragma unroll
      for (int h = 0; h < 2; h++) {
        int gm = bm + srow + h * 32;
        int rm = (gm < M) ? gm : (M - 1);
        float4 av = *(const float4*)&A[(size_t)rm * K + k0 + q4];
        As[q4 + 0][srow + h * 32] = av.x;
        As[q4 + 1][srow + h * 32] = av.y;
        As[q4 + 2][srow + h * 32] = av.z;
        As[q4 + 3][srow + h * 32] = av.w;
      }
      #pragma unroll
      for (int h = 0; h < 4; h++) {
        int gn = bn + srow + h * 32;
        float4 bv = make_float4(0.f, 0.f, 0.f, 0.f);
        if (gn < N) bv = *(const float4*)&B[(size_t)gn * K + k0 + q4];
        Bs[q4 + 0][srow + h * 32] = bv.x;
        Bs[q4 + 1][srow + h * 32] = bv.y;
        Bs[q4 + 2][srow + h * 32] = bv.z;
        Bs[q4 + 3][srow + h * 32] = bv.w;
      }
    } else {
      #pragma unroll
      for (int h = 0; h < 2; h++) {
        int gm = bm + srow + h * 32;
        int rm = (gm < M) ? gm : (M - 1);
        #pragma unroll
        for (int j = 0; j < 4; j++) {
          int gk = k0 + q4 + j;
          As[q4 + j][srow + h * 32] = (gk < K) ? A[(size_t)rm * K + gk] : 0.f;
        }
      }
      #pragma unroll
      for (int h = 0; h < 4; h++) {
        int gn = bn + srow + h * 32;
        #pragma unroll
        for (int j = 0; j < 4; j++) {
          int gk = k0 + q4 + j;
          Bs[q4 + j][srow + h * 32] =
              (gn < N && gk < K) ? B[(size_t)gn * K + gk] : 0.f;
        }
      }
    }
    __syncthreads();
    #pragma unroll
    for (int kk = 0; kk < 32; kk++) {
      float4 a4 = *(const float4*)&As[kk][tm];
      float4 b0 = *(const float4*)&Bs[kk][tn];
      float4 b1 = *(const float4*)&Bs[kk][tn + 4];
      float a[4] = {a4.x, a4.y, a4.z, a4.w};
      float b[8] = {b0.x, b0.y, b0.z, b0.w, b1.x, b1.y, b1.z, b1.w};
      #pragma unroll
      for (int i = 0; i < 4; i++)
        #pragma unroll
        for (int j = 0; j < 8; j++) acc[i][j] += a[i] * b[j];
    }
    __syncthreads();
  }

  float bb[8];
  #pragma unroll
  for (int j = 0; j < 8; j++) {
    int gn = bn + tn + j;
    bb[j] = (bias && gn < N) ? bias[gn] : 0.f;
  }
  if (bn + tn < N) {
    #pragma unroll
    for (int i = 0; i < 4; i++) {
      int gm = bm + tm + i;
      if (gm >= M) continue;
      float4 v0 = make_float4(acc[i][0] + bb[0], acc[i][1] + bb[1],
                              acc[i][2] + bb[2], acc[i][3] + bb[3]);
      float4 v1 = make_float4(acc[i][4] + bb[4], acc[i][5] + bb[5],
                              acc[i][6] + bb[6], acc[i][7] + bb[7]);
      *(float4*)&C[(size_t)gm * N + bn + tn] = v0;
      *(float4*)&C[(size_t)gm * N + bn + tn + 4] = v1;
    }
  }
}

// ---------------------------------------------------------------------------
// Prep: Wall = [WxF; WxB] (192x128), ball = [bxF; bxB],
//       Wxp = lstm_Wx zero-padded K 167 -> 192 (512 x 192),
//       Wpk = lstm_Wh packed into MFMA B-fragment order, bf16 pairs:
//       Wpk[fg][lane][p] with fg = w*16 + nt*4 + kt;
//       n = 64w + 16nt + (lane&15); k = 32kt + 8(lane>>4) + 2p(+1).
// ---------------------------------------------------------------------------
__global__ __launch_bounds__(256) void k_prep(const float* __restrict__ WxF,
    const float* __restrict__ WxB, const float* __restrict__ bxF,
    const float* __restrict__ bxB, const float* __restrict__ lstm_Wx,
    const float* __restrict__ lstm_Wh,
    float* __restrict__ Wall, float* __restrict__ ball,
    float* __restrict__ Wxp, u32* __restrict__ Wpk) {
  int i = blockIdx.x * 256 + threadIdx.x;
  if (i < 96 * 128) Wall[i] = WxF[i];
  else if (i < 192 * 128) Wall[i] = WxB[i - 96 * 128];
  if (i < 96) ball[i] = bxF[i];
  else if (i < 192) ball[i] = bxB[i - 96];
  if (i < 512 * LIN_P) {
    int n = i / LIN_P, k = i - n * LIN_P;
    Wxp[i] = (k < LIN_D) ? lstm_Wx[n * LIN_D + k] : 0.f;
  }
  if (i < 32768) {
    int fg = i >> 8, l = (i >> 2) & 63, p = i & 3;
    int w = fg >> 4, nt = (fg >> 2) & 3, kt = fg & 3;
    int n = 64 * w + 16 * nt + (l & 15);
    int k = 32 * kt + 8 * (l >> 4) + 2 * p;
    u32 a  = __float_as_uint(lstm_Wh[n * 128 + k]);
    u32 bq = __float_as_uint(lstm_Wh[n * 128 + k + 1]);
    a  = (a  + 0x7FFFu + ((a  >> 16) & 1u)) >> 16;
    bq = (bq + 0x7FFFu + ((bq >> 16) & 1u)) >> 16;
    Wpk[i] = a | (bq << 16);
  }
}

// ---------------------------------------------------------------------------
// Tree: gather 15 rows of E', bottom-up subtree sums, node max. 2 trees/block.
// ---------------------------------------------------------------------------
__global__ __launch_bounds__(256) void k_tree(const int* __restrict__ ast,
    const float* __restrict__ Ep, const float* __restrict__ Wc_b,
    float* __restrict__ x) {
  int lt = threadIdx.x >> 7;      // 0/1
  int d  = threadIdx.x & 127;
  int tree = blockIdx.x * 2 + lt;
  __shared__ int toks[2][15];
  if (d < 15) toks[lt][d] = ast[(size_t)tree * 15 + d];
  __syncthreads();
  float e[15];
  #pragma unroll
  for (int n = 0; n < 15; n++) e[n] = Ep[(size_t)toks[lt][n] * 128 + d];
  float b = Wc_b[d];
  float s3 = e[3] + e[7] + e[8],  s4 = e[4] + e[9] + e[10];
  float s5 = e[5] + e[11] + e[12], s6 = e[6] + e[13] + e[14];
  float s1 = e[1] + s3 + s4, s2 = e[2] + s5 + s6;
  float s0 = e[0] + s1 + s2;
  float ml = fmaxf(fmaxf(fmaxf(e[7], e[8]), fmaxf(e[9], e[10])),
                   fmaxf(fmaxf(e[11], e[12]), fmaxf(e[13], e[14]))) + b;
  float mm = fmaxf(fmaxf(s3, s4), fmaxf(s5, s6)) + 3.f * b;
  float mt = fmaxf(s1, s2) + 7.f * b;
  float m = fmaxf(fmaxf(ml, mm), fmaxf(mt, s0 + 15.f * b));
  x[(size_t)tree * 128 + d] = m;
}

// ---------------------------------------------------------------------------
// GRU recurrence, one block per (sequence, direction). Hidden=32, gates=96.
// ---------------------------------------------------------------------------
__global__ __launch_bounds__(128) void k_gru(const float* __restrict__ xe_all,
    const float* __restrict__ WhF, const float* __restrict__ WhB,
    const float* __restrict__ bhF, const float* __restrict__ bhB,
    float* __restrict__ code) {
  int bsq = blockIdx.x >> 1, dir = blockIdx.x & 1;
  int g = threadIdx.x;
  __shared__ float whs[96 * 32];
  __shared__ float h_lds[32];
  __shared__ float rz[64];
  __shared__ float nn[32];
  const float* Wh = dir ? WhB : WhF;
  const float* bh = dir ? bhB : bhF;
  for (int i = g; i < 96 * 32; i += 128) whs[i] = Wh[i];
  if (g < 32) h_lds[g] = 0.f;
  __syncthreads();
  float w[32]; float bhv = 0.f, mxv = -1e30f;
  if (g < 96) {
    #pragma unroll
    for (int j = 0; j < 32; j++) w[j] = whs[g * 32 + j];
    bhv = bh[g];
  }
  for (int s = 0; s < 16; s++) {
    int t = dir ? (15 - s) : s;
    const float* xe = xe_all + ((size_t)(bsq * 16 + t)) * 192 + dir * 96;
    float gh = bhv, xv = 0.f;
    if (g < 96) {
      xv = xe[g];
      #pragma unroll
      for (int j = 0; j < 32; j++) gh += w[j] * h_lds[j];
    }
    if (g < 64) rz[g] = 1.f / (1.f + expf(-(xv + gh)));
    __syncthreads();
    if (g >= 64 && g < 96) nn[g - 64] = tanhf(xv + rz[g - 64] * gh);
    __syncthreads();
    if (g < 32) {
      float z = rz[g + 32];
      float hn = (1.f - z) * nn[g] + z * h_lds[g];
      mxv = fmaxf(mxv, hn);
      h_lds[g] = hn;
    }
    __syncthreads();
  }
  if (g < 32) code[(size_t)bsq * 64 + dir * 32 + g] = mxv;
}

// ---------------------------------------------------------------------------
// Build lin = [c_embed(101) | code(64) | cur_result(2) | 0-pad to 192]
// ---------------------------------------------------------------------------
__global__ __launch_bounds__(256) void k_lin(const float* __restrict__ c_embed,
    const float* __restrict__ code, const float* __restrict__ cur,
    float* __restrict__ lin) {
  int i = blockIdx.x * 256 + threadIdx.x;
  if (i >= NROW * LIN_P) return;
  int row = i / LIN_P, j = i - row * LIN_P;
  float v;
  if (j < 101) v = c_embed[row * 101 + j];
  else if (j < 165) v = code[row * 64 + (j - 101)];
  else if (j < 167) v = cur[row * 2 + (j - 165)];
  else v = 0.f;
  lin[i] = v;
}

// ---------------------------------------------------------------------------
// LSTM v10 (MFMA): 32 blocks x 512 threads (8 waves, 2/SIMD).
// Per step per block: gates(512) = h(128) @ Wh^T via mfma_f32_16x16x32_bf16,
// M=16 with only row 0 real (A rows 1-15 zeroed). Wave w owns N-slice
// 64w..64w+63: 4 N-tiles x 4 K-tiles = 16 MFMA/step, B-frags (weights)
// held in 16 named short8 registers loaded once (MFMA operands - the one
// pattern the allocator keeps resident; R2-R9's scalar-FMA attempts all
// spilled). xe+bh folded into the MFMA C operand. D row0 = lanes 0-15
// reg 0 (verified layout: col=lane&15, row=(lane>>4)*4+reg).
// h re-packed bf16 (RNE) into 256B LDS per step. No libm.
// ---------------------------------------------------------------------------
#define LOG2E 1.4426950408889634f
__device__ __forceinline__ float fsig(float x) {
  return __builtin_amdgcn_rcpf(1.f + __builtin_amdgcn_exp2f(-LOG2E * x));
}
__device__ __forceinline__ float ftanh(float x) {
  return 2.f * __builtin_amdgcn_rcpf(
             1.f + __builtin_amdgcn_exp2f(-2.f * LOG2E * x)) - 1.f;
}
#define MFMA __builtin_amdgcn_mfma_f32_16x16x32_bf16

__global__ __launch_bounds__(512, 2) void k_lstm(
    const float* __restrict__ xeL, const u32* __restrict__ Wpk,
    const float* __restrict__ bh, float* __restrict__ lout) {
  __shared__ float ga[512];
  __shared__ s16x8 hl8[16];          // h as 128 bf16 (256 B)
  short* hls = (short*)hl8;
  int b = blockIdx.x, t = threadIdx.x;
  int w = t >> 6, lane = t & 63;
  // --- load this wave's 16 weight B-fragments (64 VGPR) once ---
  const s16x8* WB = (const s16x8*)Wpk + (size_t)w * 16 * 64 + lane;
  s16x8 B0  = WB[0 * 64],  B1  = WB[1 * 64],  B2  = WB[2 * 64],  B3  = WB[3 * 64];
  s16x8 B4  = WB[4 * 64],  B5  = WB[5 * 64],  B6  = WB[6 * 64],  B7  = WB[7 * 64];
  s16x8 B8  = WB[8 * 64],  B9  = WB[9 * 64],  B10 = WB[10 * 64], B11 = WB[11 * 64];
  s16x8 B12 = WB[12 * 64], B13 = WB[13 * 64], B14 = WB[14 * 64], B15 = WB[15 * 64];

  int gbase = 64 * w + lane;         // lane<16: gates gbase, +16, +32, +48
  float bhv0 = 0, bhv1 = 0, bhv2 = 0, bhv3 = 0;
  float xe0 = 0, xe1 = 0, xe2 = 0, xe3 = 0;
  const float* xrow = xeL + (size_t)b * 50 * 512;
  if (lane < 16) {
    bhv0 = bh[gbase]; bhv1 = bh[gbase + 16];
    bhv2 = bh[gbase + 32]; bhv3 = bh[gbase + 48];
    xe0 = xrow[gbase]; xe1 = xrow[gbase + 16];
    xe2 = xrow[gbase + 32]; xe3 = xrow[gbase + 48];
  }
  float c = 0.f;
  if (t < 128) hls[t] = 0;
  __syncthreads();
  const s16x8 zz = {0, 0, 0, 0, 0, 0, 0, 0};
  const bool arow = (lane & 15) == 0;
  const int asel = lane >> 4;        // 0..3
  for (int step = 0; step < 50; step++) {
    // A-frags: row 0 = h (bf16), rows 1-15 zero
    s16x8 a0 = arow ? hl8[asel]      : zz;
    s16x8 a1 = arow ? hl8[4 + asel]  : zz;
    s16x8 a2 = arow ? hl8[8 + asel]  : zz;
    s16x8 a3 = arow ? hl8[12 + asel] : zz;
    f32x4 acc0 = {0, 0, 0, 0}, acc1 = {0, 0, 0, 0};
    f32x4 acc2 = {0, 0, 0, 0}, acc3 = {0, 0, 0, 0};
    if (lane < 16) {
      acc0[0] = xe0 + bhv0; acc1[0] = xe1 + bhv1;
      acc2[0] = xe2 + bhv2; acc3[0] = xe3 + bhv3;
    }
    if (step < 49 && lane < 16) {     // prefetch next step's xe under MFMA
      const float* xn = xrow + (size_t)(step + 1) * 512;
      xe0 = xn[gbase]; xe1 = xn[gbase + 16];
      xe2 = xn[gbase + 32]; xe3 = xn[gbase + 48];
    }
    acc0 = MFMA(a0, B0,  acc0, 0, 0, 0); acc0 = MFMA(a1, B1,  acc0, 0, 0, 0);
    acc0 = MFMA(a2, B2,  acc0, 0, 0, 0); acc0 = MFMA(a3, B3,  acc0, 0, 0, 0);
    acc1 = MFMA(a0, B4,  acc1, 0, 0, 0); acc1 = MFMA(a1, B5,  acc1, 0, 0, 0);
    acc1 = MFMA(a2, B6,  acc1, 0, 0, 0); acc1 = MFMA(a3, B7,  acc1, 0, 0, 0);
    acc2 = MFMA(a0, B8,  acc2, 0, 0, 0); acc2 = MFMA(a1, B9,  acc2, 0, 0, 0);
    acc2 = MFMA(a2, B10, acc2, 0, 0, 0); acc2 = MFMA(a3, B11, acc2, 0, 0, 0);
    acc3 = MFMA(a0, B12, acc3, 0, 0, 0); acc3 = MFMA(a1, B13, acc3, 0, 0, 0);
    acc3 = MFMA(a2, B14, acc3, 0, 0, 0); acc3 = MFMA(a3, B15, acc3, 0, 0, 0);
    if (lane < 16) {
      ga[gbase]      = acc0[0];
      ga[gbase + 16] = acc1[0];
      ga[gbase + 32] = acc2[0];
      ga[gbase + 48] = acc3[0];
    }
    __syncthreads();
    if (t < 128) {
      float iv = fsig(ga[t]);
      float fv = fsig(ga[t + 128]);
      float gv = ftanh(ga[t + 256]);
      float ov = fsig(ga[t + 384]);
      c = fv * c + iv * gv;
      float h = ov * ftanh(c);
      lout[((size_t)b * 50 + step) * 128 + t] = h;
      u32 x = __float_as_uint(h);
      hls[t] = (short)((x + 0x7FFFu + ((x >> 16) & 1u)) >> 16);
    }
    __syncthreads();
  }
}

// ---------------------------------------------------------------------------
// Prediction head: p1 = lout . (pred_w^T tc) + tc . pred_b
// ---------------------------------------------------------------------------
__global__ __launch_bounds__(128) void k_pred(const float* __restrict__ lout,
    const float* __restrict__ pred_w, const float* __restrict__ pred_b,
    const float* __restrict__ tc, const float* __restrict__ result,
    float* __restrict__ out, float* __restrict__ fpbuf, float* __restrict__ mbuf) {
  int row = blockIdx.x; int k = threadIdx.x;
  __shared__ float tcs[101];
  __shared__ float r1[128], r2[128], r3[128];
  if (k < 101) tcs[k] = tc[(size_t)row * 101 + k];
  __syncthreads();
  float lk = lout[(size_t)row * 128 + k];
  float acc = 0.f;
  for (int c = 0; c < 101; c++) acc += tcs[c] * pred_w[c * 128 + k];
  float v = acc * lk;
  float pb = (k < 101) ? tcs[k] * pred_b[k] : 0.f;
  float nc = (k < 101) ? tcs[k] : 0.f;
  r1[k] = v; r2[k] = pb; r3[k] = nc;
  __syncthreads();
  for (int st = 64; st > 0; st >>= 1) {
    if (k < st) { r1[k] += r1[k + st]; r2[k] += r2[k + st]; r3[k] += r3[k + st]; }
    __syncthreads();
  }
  if (k == 0) {
    float ncon = r3[0];
    float m = (ncon > 0.f) ? 1.f : 0.f;
    float fp = (r1[0] + r2[0]) / fmaxf(ncon, 1.f);
    fpbuf[row] = fp; mbuf[row] = m;
    out[1 + row] = m / (1.f + expf(-fp));
    out[1 + NROW + row] = result[row] * m;
  }
}

// ---------------------------------------------------------------------------
// Loss reduction (single block, deterministic tree reduce)
// ---------------------------------------------------------------------------
__global__ __launch_bounds__(256) void k_loss(const float* __restrict__ fpbuf,
    const float* __restrict__ mbuf, const float* __restrict__ result,
    float* __restrict__ out) {
  __shared__ float sb[256], sm[256];
  int k = threadIdx.x;
  float ab = 0.f, am = 0.f;
  for (int r = k; r < NROW; r += 256) {
    float fp = fpbuf[r], m = mbuf[r], res = result[r];
    float bce = fmaxf(fp, 0.f) - fp * res + log1pf(expf(-fabsf(fp)));
    ab += bce * m; am += m;
  }
  sb[k] = ab; sm[k] = am;
  __syncthreads();
  for (int st = 128; st > 0; st >>= 1) {
    if (k < st) { sb[k] += sb[k + st]; sm[k] += sm[k + st]; }
    __syncthreads();
  }
  if (k == 0) out[0] = sb[0] / fmaxf(sm[0], 1.f);
}

// ---------------------------------------------------------------------------
extern "C" void kernel_launch(void* const* d_in, const int* in_sizes, int n_in,
                              void* d_out, int out_size, void* d_ws, size_t ws_size,
                              hipStream_t stream) {
  (void)in_sizes; (void)n_in; (void)out_size; (void)ws_size;
  const int*   ast      = (const int*)  d_in[2];
  const float* target_c = (const float*)d_in[3];
  const float* c_embed  = (const float*)d_in[4];
  const float* cur_res  = (const float*)d_in[5];
  const float* result   = (const float*)d_in[6];
  const float* emb      = (const float*)d_in[7];
  const float* Wc_w     = (const float*)d_in[8];
  const float* Wc_b     = (const float*)d_in[9];
  const float* gru_WxF  = (const float*)d_in[10];
  const float* gru_WhF  = (const float*)d_in[11];
  const float* gru_bxF  = (const float*)d_in[12];
  const float* gru_bhF  = (const float*)d_in[13];
  const float* gru_WxB  = (const float*)d_in[14];
  const float* gru_WhB  = (const float*)d_in[15];
  const float* gru_bxB  = (const float*)d_in[16];
  const float* gru_bhB  = (const float*)d_in[17];
  const float* lstm_Wx  = (const float*)d_in[18];
  const float* lstm_Wh  = (const float*)d_in[19];
  const float* lstm_bx  = (const float*)d_in[20];
  const float* lstm_bh  = (const float*)d_in[21];
  const float* pred_w   = (const float*)d_in[22];
  const float* pred_b   = (const float*)d_in[23];
  float* out = (float*)d_out;

  float* W = (float*)d_ws;
  float* Ep     = W;                 // 6,400,000 (VOCAB*128)
  float* xe_all = W;                 // alias: 25600*192 = 4,915,200 <= Ep size
  float* x      = W + 6400000;       // 3,276,800
  float* Wall   = W + 9676800;       // 24,576
  float* ball   = W + 9701376;       // 192
  float* Wxp    = W + 9701568;       // 98,304 (512 x 192)
  float* code   = W + 9799872;       // 102,400
  float* lin    = W + 9902272;       // 307,200 (1600 x 192)
  float* xeL    = W + 10209472;      // 819,200
  float* lout   = W + 11028672;      // 204,800
  float* fpbuf  = W + 11233472;      // 1,600
  float* mbuf   = W + 11235072;      // 1,600
  u32*   Wpk    = (u32*)(W + 11236672); // 32,768 u32 (MFMA-packed bf16 Wh)

  // 1. E' = emb @ Wc_w^T   (vocab-level projection)
  sgemm_nt<<<dim3(1, 782), 256, 0, stream>>>(emb, Wc_w, nullptr, Ep, VOCAB, 128, 128);
  // 2. weight prep (Wx pad 167->192, Wh -> MFMA bf16 fragments)
  k_prep<<<384, 256, 0, stream>>>(gru_WxF, gru_WxB, gru_bxF, gru_bxB, lstm_Wx,
                                  lstm_Wh, Wall, ball, Wxp, Wpk);
  // 3. tree gather/sum/max -> x (25600 x 128)
  k_tree<<<NTREE / 2, 256, 0, stream>>>(ast, Ep, Wc_b, x);
  // 4. xe_all = x @ Wall^T + ball  (25600 x 192)  [aliases Ep region]
  sgemm_nt<<<dim3(2, 400), 256, 0, stream>>>(x, Wall, ball, xe_all, NTREE, 192, 128);
  // 5. GRU recurrence + time max -> code (1600 x 64)
  k_gru<<<NROW * 2, 128, 0, stream>>>(xe_all, gru_WhF, gru_WhB, gru_bhF, gru_bhB, code);
  // 6. lin build (1600 x 192, zero-padded)
  k_lin<<<(NROW * LIN_P + 255) / 256, 256, 0, stream>>>(c_embed, code, cur_res, lin);
  // 7. xeL = lin @ Wxp^T + lstm_bx (1600 x 512, K=192 vector path)
  sgemm_nt<<<dim3(4, 25), 256, 0, stream>>>(lin, Wxp, lstm_bx, xeL, NROW, 512, LIN_P);
  // 8. LSTM recurrence -> lout (1600 x 128)  [MFMA, weights as B-fragments]
  k_lstm<<<BS, 512, 0, stream>>>(xeL, Wpk, lstm_bh, lout);
  // 9. prediction head -> out[1..], fpbuf, mbuf
  k_pred<<<NROW, 128, 0, stream>>>(lout, pred_w, pred_b, target_c, result,
                                   out, fpbuf, mbuf);
  // 10. loss -> out[0]
  k_loss<<<1, 256, 0, stream>>>(fpbuf, mbuf, result, out);
}

// Round 12
// 205.314 us; speedup vs baseline: 1.1765x; 1.0145x over previous
//
#include <hip/hip_runtime.h>
#include <hip/hip_bf16.h>
#include <math.h>

// Problem constants
#define BS 32
#define SEQ 50
#define ML 16
#define NN 15
#define NTREE (BS*SEQ*ML)     // 25600
#define NROW (BS*SEQ)         // 1600
#define VOCAB 50000
#define EMB 128
#define ENC 128
#define GH 32
#define NC 100
#define LH 128
#define LIN_D 167             // 101 + 64 + 2
#define LIN_P 192             // padded K for the xeL GEMM (vector path)

typedef float f32x4 __attribute__((ext_vector_type(4)));
typedef short s16x8 __attribute__((ext_vector_type(8)));
typedef unsigned int u32;

// ---------------------------------------------------------------------------
// fp32 GEMM: C[M][N] = A[M][K] @ B[N][K]^T (+ bias[N])
// BM=64 x BN=128 tile, BK=32, 256 threads, 4x8 per thread.
// ---------------------------------------------------------------------------
__global__ __launch_bounds__(256) void sgemm_nt(const float* __restrict__ A,
    const float* __restrict__ B, const float* __restrict__ bias,
    float* __restrict__ C, int M, int N, int K) {
  __shared__ float As[32][68];    // [k][m]
  __shared__ float Bs[32][132];   // [k][n]
  const int bm = blockIdx.y * 64, bn = blockIdx.x * 128;
  const int tid = threadIdx.x;
  const int tm = (tid >> 4) << 2;   // 0..60
  const int tn = (tid & 15) << 3;   // 0..120
  const int srow = tid >> 3;        // 0..31
  const int q4 = (tid & 7) << 2;    // 0,4,..,28
  const bool vec_ok = ((K & 3) == 0);

  float acc[4][8];
  #pragma unroll
  for (int i = 0; i < 4; i++)
    #pragma unroll
    for (int j = 0; j < 8; j++) acc[i][j] = 0.f;

  for (int k0 = 0; k0 < K; k0 += 32) {
    if (vec_ok && (k0 + 32 <= K)) {
      #pragma unroll
      for (int h = 0; h < 2; h++) {
        int gm = bm + srow + h * 32;
        int rm = (gm < M) ? gm : (M - 1);
        float4 av = *(const float4*)&A[(size_t)rm * K + k0 + q4];
        As[q4 + 0][srow + h * 32] = av.x;
        As[q4 + 1][srow + h * 32] = av.y;
        As[q4 + 2][srow + h * 32] = av.z;
        As[q4 + 3][srow + h * 32] = av.w;
      }
      #pragma unroll
      for (int h = 0; h < 4; h++) {
        int gn = bn + srow + h * 32;
        float4 bv = make_float4(0.f, 0.f, 0.f, 0.f);
        if (gn < N) bv = *(const float4*)&B[(size_t)gn * K + k0 + q4];
        Bs[q4 + 0][srow + h * 32] = bv.x;
        Bs[q4 + 1][srow + h * 32] = bv.y;
        Bs[q4 + 2][srow + h * 32] = bv.z;
        Bs[q4 + 3][srow + h * 32] = bv.w;
      }
    } else {
      #pragma unroll
      for (int h = 0; h < 2; h++) {
        int gm = bm + srow + h * 32;
        int rm = (gm < M) ? gm : (M - 1);
        #pragma unroll
        for (int j = 0; j < 4; j++) {
          int gk = k0 + q4 + j;
          As[q4 + j][srow + h * 32] = (gk < K) ? A[(size_t)rm * K + gk] : 0.f;
        }
      }
      #pragma unroll
      for (int h = 0; h < 4; h++) {
        int gn = bn + srow + h * 32;
        #pragma unroll
        for (int j = 0; j < 4; j++) {
          int gk = k0 + q4 + j;
          Bs[q4 + j][srow + h * 32] =
              (gn < N && gk < K) ? B[(size_t)gn * K + gk] : 0.f;
        }
      }
    }
    __syncthreads();
    #pragma unroll
    for (int kk = 0; kk < 32; kk++) {
      float4 a4 = *(const float4*)&As[kk][tm];
      float4 b0 = *(const float4*)&Bs[kk][tn];
      float4 b1 = *(const float4*)&Bs[kk][tn + 4];
      float a[4] = {a4.x, a4.y, a4.z, a4.w};
      float b[8] = {b0.x, b0.y, b0.z, b0.w, b1.x, b1.y, b1.z, b1.w};
      #pragma unroll
      for (int i = 0; i < 4; i++)
        #pragma unroll
        for (int j = 0; j < 8; j++) acc[i][j] += a[i] * b[j];
    }
    __syncthreads();
  }

  float bb[8];
  #pragma unroll
  for (int j = 0; j < 8; j++) {
    int gn = bn + tn + j;
    bb[j] = (bias && gn < N) ? bias[gn] : 0.f;
  }
  if (bn + tn < N) {
    #pragma unroll
    for (int i = 0; i < 4; i++) {
      int gm = bm + tm + i;
      if (gm >= M) continue;
      float4 v0 = make_float4(acc[i][0] + bb[0], acc[i][1] + bb[1],
                              acc[i][2] + bb[2], acc[i][3] + bb[3]);
      float4 v1 = make_float4(acc[i][4] + bb[4], acc[i][5] + bb[5],
                              acc[i][6] + bb[6], acc[i][7] + bb[7]);
      *(float4*)&C[(size_t)gm * N + bn + tn] = v0;
      *(float4*)&C[(size_t)gm * N + bn + tn + 4] = v1;
    }
  }
}

// ---------------------------------------------------------------------------
// Prep: Wall = [WxF; WxB] (192x128), ball = [bxF; bxB],
//       Wxp = lstm_Wx zero-padded K 167 -> 192 (512 x 192),
//       Wpk = lstm_Wh packed into MFMA B-fragment order, bf16 pairs.
// ---------------------------------------------------------------------------
__global__ __launch_bounds__(256) void k_prep(const float* __restrict__ WxF,
    const float* __restrict__ WxB, const float* __restrict__ bxF,
    const float* __restrict__ bxB, const float* __restrict__ lstm_Wx,
    const float* __restrict__ lstm_Wh,
    float* __restrict__ Wall, float* __restrict__ ball,
    float* __restrict__ Wxp, u32* __restrict__ Wpk) {
  int i = blockIdx.x * 256 + threadIdx.x;
  if (i < 96 * 128) Wall[i] = WxF[i];
  else if (i < 192 * 128) Wall[i] = WxB[i - 96 * 128];
  if (i < 96) ball[i] = bxF[i];
  else if (i < 192) ball[i] = bxB[i - 96];
  if (i < 512 * LIN_P) {
    int n = i / LIN_P, k = i - n * LIN_P;
    Wxp[i] = (k < LIN_D) ? lstm_Wx[n * LIN_D + k] : 0.f;
  }
  if (i < 32768) {
    int fg = i >> 8, l = (i >> 2) & 63, p = i & 3;
    int w = fg >> 4, nt = (fg >> 2) & 3, kt = fg & 3;
    int n = 64 * w + 16 * nt + (l & 15);
    int k = 32 * kt + 8 * (l >> 4) + 2 * p;
    u32 a  = __float_as_uint(lstm_Wh[n * 128 + k]);
    u32 bq = __float_as_uint(lstm_Wh[n * 128 + k + 1]);
    a  = (a  + 0x7FFFu + ((a  >> 16) & 1u)) >> 16;
    bq = (bq + 0x7FFFu + ((bq >> 16) & 1u)) >> 16;
    Wpk[i] = a | (bq << 16);
  }
}

// ---------------------------------------------------------------------------
// Tree: gather 15 rows of E', bottom-up subtree sums, node max. 2 trees/block.
// ---------------------------------------------------------------------------
__global__ __launch_bounds__(256) void k_tree(const int* __restrict__ ast,
    const float* __restrict__ Ep, const float* __restrict__ Wc_b,
    float* __restrict__ x) {
  int lt = threadIdx.x >> 7;      // 0/1
  int d  = threadIdx.x & 127;
  int tree = blockIdx.x * 2 + lt;
  __shared__ int toks[2][15];
  if (d < 15) toks[lt][d] = ast[(size_t)tree * 15 + d];
  __syncthreads();
  float e[15];
  #pragma unroll
  for (int n = 0; n < 15; n++) e[n] = Ep[(size_t)toks[lt][n] * 128 + d];
  float b = Wc_b[d];
  float s3 = e[3] + e[7] + e[8],  s4 = e[4] + e[9] + e[10];
  float s5 = e[5] + e[11] + e[12], s6 = e[6] + e[13] + e[14];
  float s1 = e[1] + s3 + s4, s2 = e[2] + s5 + s6;
  float s0 = e[0] + s1 + s2;
  float ml = fmaxf(fmaxf(fmaxf(e[7], e[8]), fmaxf(e[9], e[10])),
                   fmaxf(fmaxf(e[11], e[12]), fmaxf(e[13], e[14]))) + b;
  float mm = fmaxf(fmaxf(s3, s4), fmaxf(s5, s6)) + 3.f * b;
  float mt = fmaxf(s1, s2) + 7.f * b;
  float m = fmaxf(fmaxf(ml, mm), fmaxf(mt, s0 + 15.f * b));
  x[(size_t)tree * 128 + d] = m;
}

// ---------------------------------------------------------------------------
// GRU recurrence, one block per (sequence, direction). Hidden=32, gates=96.
// ---------------------------------------------------------------------------
__global__ __launch_bounds__(128) void k_gru(const float* __restrict__ xe_all,
    const float* __restrict__ WhF, const float* __restrict__ WhB,
    const float* __restrict__ bhF, const float* __restrict__ bhB,
    float* __restrict__ code) {
  int bsq = blockIdx.x >> 1, dir = blockIdx.x & 1;
  int g = threadIdx.x;
  __shared__ float whs[96 * 32];
  __shared__ float h_lds[32];
  __shared__ float rz[64];
  __shared__ float nn[32];
  const float* Wh = dir ? WhB : WhF;
  const float* bh = dir ? bhB : bhF;
  for (int i = g; i < 96 * 32; i += 128) whs[i] = Wh[i];
  if (g < 32) h_lds[g] = 0.f;
  __syncthreads();
  float w[32]; float bhv = 0.f, mxv = -1e30f;
  if (g < 96) {
    #pragma unroll
    for (int j = 0; j < 32; j++) w[j] = whs[g * 32 + j];
    bhv = bh[g];
  }
  for (int s = 0; s < 16; s++) {
    int t = dir ? (15 - s) : s;
    const float* xe = xe_all + ((size_t)(bsq * 16 + t)) * 192 + dir * 96;
    float gh = bhv, xv = 0.f;
    if (g < 96) {
      xv = xe[g];
      #pragma unroll
      for (int j = 0; j < 32; j++) gh += w[j] * h_lds[j];
    }
    if (g < 64) rz[g] = 1.f / (1.f + expf(-(xv + gh)));
    __syncthreads();
    if (g >= 64 && g < 96) nn[g - 64] = tanhf(xv + rz[g - 64] * gh);
    __syncthreads();
    if (g < 32) {
      float z = rz[g + 32];
      float hn = (1.f - z) * nn[g] + z * h_lds[g];
      mxv = fmaxf(mxv, hn);
      h_lds[g] = hn;
    }
    __syncthreads();
  }
  if (g < 32) code[(size_t)bsq * 64 + dir * 32 + g] = mxv;
}

// ---------------------------------------------------------------------------
// Build lin = [c_embed(101) | code(64) | cur_result(2) | 0-pad to 192]
// ---------------------------------------------------------------------------
__global__ __launch_bounds__(256) void k_lin(const float* __restrict__ c_embed,
    const float* __restrict__ code, const float* __restrict__ cur,
    float* __restrict__ lin) {
  int i = blockIdx.x * 256 + threadIdx.x;
  if (i >= NROW * LIN_P) return;
  int row = i / LIN_P, j = i - row * LIN_P;
  float v;
  if (j < 101) v = c_embed[row * 101 + j];
  else if (j < 165) v = code[row * 64 + (j - 101)];
  else if (j < 167) v = cur[row * 2 + (j - 165)];
  else v = 0.f;
  lin[i] = v;
}

// ---------------------------------------------------------------------------
// LSTM v11 (MFMA, all-on-chip loop): 32 blocks x 512 threads, 1 block/CU.
// R10 lesson: per-step __syncthreads drains vmcnt(0), so any global op in
// the loop (lout store, xe prefetch) costs an L2 round-trip per barrier.
// Fix: stage the whole 50x512 xe slice into LDS up front (100 KB), keep the
// h history in LDS (25.6 KB), dump to global once at the end. Loop touches
// only LDS -> barriers drain lgkmcnt only. Gate activations moved into the
// MFMA waves (gate type is wave-uniform: w>>1 = i/f/g/o).
// ---------------------------------------------------------------------------
#define LOG2E 1.4426950408889634f
__device__ __forceinline__ float fsig(float x) {
  return __builtin_amdgcn_rcpf(1.f + __builtin_amdgcn_exp2f(-LOG2E * x));
}
__device__ __forceinline__ float ftanh(float x) {
  return 2.f * __builtin_amdgcn_rcpf(
             1.f + __builtin_amdgcn_exp2f(-2.f * LOG2E * x)) - 1.f;
}
#define MFMA __builtin_amdgcn_mfma_f32_16x16x32_bf16

__global__ __launch_bounds__(512) void k_lstm(
    const float* __restrict__ xeL, const u32* __restrict__ Wpk,
    const float* __restrict__ bh, float* __restrict__ lout) {
  __shared__ float xl[SEQ * 512];    // 102400 B: staged xe (incl. bx)
  __shared__ float hh[SEQ * 128];    // 25600 B: h history
  __shared__ float ga[512];          // activated gates
  __shared__ s16x8 hl8[16];          // h as 128 bf16 (256 B)
  short* hls = (short*)hl8;
  int b = blockIdx.x, t = threadIdx.x;
  int w = t >> 6, lane = t & 63;
  // --- stage xe slice (coalesced) ---
  const float* xrow = xeL + (size_t)b * SEQ * 512;
  #pragma unroll 5
  for (int i = t; i < SEQ * 512; i += 512) xl[i] = xrow[i];
  // --- load this wave's 16 weight B-fragments (64 VGPR) once ---
  const s16x8* WB = (const s16x8*)Wpk + (size_t)w * 16 * 64 + lane;
  s16x8 B0  = WB[0 * 64],  B1  = WB[1 * 64],  B2  = WB[2 * 64],  B3  = WB[3 * 64];
  s16x8 B4  = WB[4 * 64],  B5  = WB[5 * 64],  B6  = WB[6 * 64],  B7  = WB[7 * 64];
  s16x8 B8  = WB[8 * 64],  B9  = WB[9 * 64],  B10 = WB[10 * 64], B11 = WB[11 * 64];
  s16x8 B12 = WB[12 * 64], B13 = WB[13 * 64], B14 = WB[14 * 64], B15 = WB[15 * 64];

  int gbase = 64 * w + lane;         // lane<16: gates gbase, +16, +32, +48
  float bhv0 = 0, bhv1 = 0, bhv2 = 0, bhv3 = 0;
  if (lane < 16) {
    bhv0 = bh[gbase]; bhv1 = bh[gbase + 16];
    bhv2 = bh[gbase + 32]; bhv3 = bh[gbase + 48];
  }
  float c = 0.f;
  if (t < 128) hls[t] = 0;
  __syncthreads();
  const s16x8 zz = {0, 0, 0, 0, 0, 0, 0, 0};
  const bool arow = (lane & 15) == 0;
  const int asel = lane >> 4;        // 0..3
  const bool tanh_gate = (w == 4 || w == 5);   // gates 256..383 = g-gate
  for (int step = 0; step < SEQ; step++) {
    // A-frags: row 0 = h (bf16), rows 1-15 zero
    s16x8 a0 = arow ? hl8[asel]      : zz;
    s16x8 a1 = arow ? hl8[4 + asel]  : zz;
    s16x8 a2 = arow ? hl8[8 + asel]  : zz;
    s16x8 a3 = arow ? hl8[12 + asel] : zz;
    f32x4 acc0 = {0, 0, 0, 0}, acc1 = {0, 0, 0, 0};
    f32x4 acc2 = {0, 0, 0, 0}, acc3 = {0, 0, 0, 0};
    if (lane < 16) {
      const float* xs = xl + step * 512;
      acc0[0] = xs[gbase]      + bhv0;
      acc1[0] = xs[gbase + 16] + bhv1;
      acc2[0] = xs[gbase + 32] + bhv2;
      acc3[0] = xs[gbase + 48] + bhv3;
    }
    acc0 = MFMA(a0, B0,  acc0, 0, 0, 0); acc0 = MFMA(a1, B1,  acc0, 0, 0, 0);
    acc0 = MFMA(a2, B2,  acc0, 0, 0, 0); acc0 = MFMA(a3, B3,  acc0, 0, 0, 0);
    acc1 = MFMA(a0, B4,  acc1, 0, 0, 0); acc1 = MFMA(a1, B5,  acc1, 0, 0, 0);
    acc1 = MFMA(a2, B6,  acc1, 0, 0, 0); acc1 = MFMA(a3, B7,  acc1, 0, 0, 0);
    acc2 = MFMA(a0, B8,  acc2, 0, 0, 0); acc2 = MFMA(a1, B9,  acc2, 0, 0, 0);
    acc2 = MFMA(a2, B10, acc2, 0, 0, 0); acc2 = MFMA(a3, B11, acc2, 0, 0, 0);
    acc3 = MFMA(a0, B12, acc3, 0, 0, 0); acc3 = MFMA(a1, B13, acc3, 0, 0, 0);
    acc3 = MFMA(a2, B14, acc3, 0, 0, 0); acc3 = MFMA(a3, B15, acc3, 0, 0, 0);
    if (lane < 16) {
      if (tanh_gate) {
        ga[gbase]      = ftanh(acc0[0]);
        ga[gbase + 16] = ftanh(acc1[0]);
        ga[gbase + 32] = ftanh(acc2[0]);
        ga[gbase + 48] = ftanh(acc3[0]);
      } else {
        ga[gbase]      = fsig(acc0[0]);
        ga[gbase + 16] = fsig(acc1[0]);
        ga[gbase + 32] = fsig(acc2[0]);
        ga[gbase + 48] = fsig(acc3[0]);
      }
    }
    __syncthreads();
    if (t < 128) {
      c = ga[t + 128] * c + ga[t] * ga[t + 256];
      float h = ga[t + 384] * ftanh(c);
      hh[step * 128 + t] = h;
      u32 x = __float_as_uint(h);
      hls[t] = (short)((x + 0x7FFFu + ((x >> 16) & 1u)) >> 16);
    }
    __syncthreads();
  }
  // --- dump h history (coalesced) ---
  float* lo = lout + (size_t)b * SEQ * 128;
  #pragma unroll 4
  for (int i = t; i < SEQ * 128; i += 512) lo[i] = hh[i];
}

// ---------------------------------------------------------------------------
// Prediction head: p1 = lout . (pred_w^T tc) + tc . pred_b
// ---------------------------------------------------------------------------
__global__ __launch_bounds__(128) void k_pred(const float* __restrict__ lout,
    const float* __restrict__ pred_w, const float* __restrict__ pred_b,
    const float* __restrict__ tc, const float* __restrict__ result,
    float* __restrict__ out, float* __restrict__ fpbuf, float* __restrict__ mbuf) {
  int row = blockIdx.x; int k = threadIdx.x;
  __shared__ float tcs[101];
  __shared__ float r1[128], r2[128], r3[128];
  if (k < 101) tcs[k] = tc[(size_t)row * 101 + k];
  __syncthreads();
  float lk = lout[(size_t)row * 128 + k];
  float acc = 0.f;
  for (int c = 0; c < 101; c++) acc += tcs[c] * pred_w[c * 128 + k];
  float v = acc * lk;
  float pb = (k < 101) ? tcs[k] * pred_b[k] : 0.f;
  float nc = (k < 101) ? tcs[k] : 0.f;
  r1[k] = v; r2[k] = pb; r3[k] = nc;
  __syncthreads();
  for (int st = 64; st > 0; st >>= 1) {
    if (k < st) { r1[k] += r1[k + st]; r2[k] += r2[k + st]; r3[k] += r3[k + st]; }
    __syncthreads();
  }
  if (k == 0) {
    float ncon = r3[0];
    float m = (ncon > 0.f) ? 1.f : 0.f;
    float fp = (r1[0] + r2[0]) / fmaxf(ncon, 1.f);
    fpbuf[row] = fp; mbuf[row] = m;
    out[1 + row] = m / (1.f + expf(-fp));
    out[1 + NROW + row] = result[row] * m;
  }
}

// ---------------------------------------------------------------------------
// Loss reduction (single block, deterministic tree reduce)
// ---------------------------------------------------------------------------
__global__ __launch_bounds__(256) void k_loss(const float* __restrict__ fpbuf,
    const float* __restrict__ mbuf, const float* __restrict__ result,
    float* __restrict__ out) {
  __shared__ float sb[256], sm[256];
  int k = threadIdx.x;
  float ab = 0.f, am = 0.f;
  for (int r = k; r < NROW; r += 256) {
    float fp = fpbuf[r], m = mbuf[r], res = result[r];
    float bce = fmaxf(fp, 0.f) - fp * res + log1pf(expf(-fabsf(fp)));
    ab += bce * m; am += m;
  }
  sb[k] = ab; sm[k] = am;
  __syncthreads();
  for (int st = 128; st > 0; st >>= 1) {
    if (k < st) { sb[k] += sb[k + st]; sm[k] += sm[k + st]; }
    __syncthreads();
  }
  if (k == 0) out[0] = sb[0] / fmaxf(sm[0], 1.f);
}

// ---------------------------------------------------------------------------
extern "C" void kernel_launch(void* const* d_in, const int* in_sizes, int n_in,
                              void* d_out, int out_size, void* d_ws, size_t ws_size,
                              hipStream_t stream) {
  (void)in_sizes; (void)n_in; (void)out_size; (void)ws_size;
  const int*   ast      = (const int*)  d_in[2];
  const float* target_c = (const float*)d_in[3];
  const float* c_embed  = (const float*)d_in[4];
  const float* cur_res  = (const float*)d_in[5];
  const float* result   = (const float*)d_in[6];
  const float* emb      = (const float*)d_in[7];
  const float* Wc_w     = (const float*)d_in[8];
  const float* Wc_b     = (const float*)d_in[9];
  const float* gru_WxF  = (const float*)d_in[10];
  const float* gru_WhF  = (const float*)d_in[11];
  const float* gru_bxF  = (const float*)d_in[12];
  const float* gru_bhF  = (const float*)d_in[13];
  const float* gru_WxB  = (const float*)d_in[14];
  const float* gru_WhB  = (const float*)d_in[15];
  const float* gru_bxB  = (const float*)d_in[16];
  const float* gru_bhB  = (const float*)d_in[17];
  const float* lstm_Wx  = (const float*)d_in[18];
  const float* lstm_Wh  = (const float*)d_in[19];
  const float* lstm_bx  = (const float*)d_in[20];
  const float* lstm_bh  = (const float*)d_in[21];
  const float* pred_w   = (const float*)d_in[22];
  const float* pred_b   = (const float*)d_in[23];
  float* out = (float*)d_out;

  float* W = (float*)d_ws;
  float* Ep     = W;                 // 6,400,000 (VOCAB*128)
  float* xe_all = W;                 // alias: 25600*192 = 4,915,200 <= Ep size
  float* x      = W + 6400000;       // 3,276,800
  float* Wall   = W + 9676800;       // 24,576
  float* ball   = W + 9701376;       // 192
  float* Wxp    = W + 9701568;       // 98,304 (512 x 192)
  float* code   = W + 9799872;       // 102,400
  float* lin    = W + 9902272;       // 307,200 (1600 x 192)
  float* xeL    = W + 10209472;      // 819,200
  float* lout   = W + 11028672;      // 204,800
  float* fpbuf  = W + 11233472;      // 1,600
  float* mbuf   = W + 11235072;      // 1,600
  u32*   Wpk    = (u32*)(W + 11236672); // 32,768 u32 (MFMA-packed bf16 Wh)

  // 1. E' = emb @ Wc_w^T   (vocab-level projection)
  sgemm_nt<<<dim3(1, 782), 256, 0, stream>>>(emb, Wc_w, nullptr, Ep, VOCAB, 128, 128);
  // 2. weight prep (Wx pad 167->192, Wh -> MFMA bf16 fragments)
  k_prep<<<384, 256, 0, stream>>>(gru_WxF, gru_WxB, gru_bxF, gru_bxB, lstm_Wx,
                                  lstm_Wh, Wall, ball, Wxp, Wpk);
  // 3. tree gather/sum/max -> x (25600 x 128)
  k_tree<<<NTREE / 2, 256, 0, stream>>>(ast, Ep, Wc_b, x);
  // 4. xe_all = x @ Wall^T + ball  (25600 x 192)  [aliases Ep region]
  sgemm_nt<<<dim3(2, 400), 256, 0, stream>>>(x, Wall, ball, xe_all, NTREE, 192, 128);
  // 5. GRU recurrence + time max -> code (1600 x 64)
  k_gru<<<NROW * 2, 128, 0, stream>>>(xe_all, gru_WhF, gru_WhB, gru_bhF, gru_bhB, code);
  // 6. lin build (1600 x 192, zero-padded)
  k_lin<<<(NROW * LIN_P + 255) / 256, 256, 0, stream>>>(c_embed, code, cur_res, lin);
  // 7. xeL = lin @ Wxp^T + lstm_bx (1600 x 512, K=192 vector path)
  sgemm_nt<<<dim3(4, 25), 256, 0, stream>>>(lin, Wxp, lstm_bx, xeL, NROW, 512, LIN_P);
  // 8. LSTM recurrence -> lout (1600 x 128)  [MFMA, all-on-chip loop]
  k_lstm<<<BS, 512, 0, stream>>>(xeL, Wpk, lstm_bh, lout);
  // 9. prediction head -> out[1..], fpbuf, mbuf
  k_pred<<<NROW, 128, 0, stream>>>(lout, pred_w, pred_b, target_c, result,
                                   out, fpbuf, mbuf);
  // 10. loss -> out[0]
  k_loss<<<1, 256, 0, stream>>>(fpbuf, mbuf, result, out);
}

// Round 13
// 149.006 us; speedup vs baseline: 1.6212x; 1.3779x over previous
//
#include <hip/hip_runtime.h>
#include <hip/hip_bf16.h>
#include <math.h>

// Problem constants
#define BS 32
#define SEQ 50
#define ML 16
#define NN 15
#define NTREE (BS*SEQ*ML)     // 25600
#define NROW (BS*SEQ)         // 1600
#define VOCAB 50000
#define EMB 128
#define ENC 128
#define GH 32
#define NC 100
#define LH 128
#define LIN_D 167             // 101 + 64 + 2
#define LIN_P 192             // padded K for the xeL GEMM (vector path)

typedef float f32x4 __attribute__((ext_vector_type(4)));
typedef short s16x8 __attribute__((ext_vector_type(8)));
typedef unsigned int u32;
typedef u32 u32x4v __attribute__((ext_vector_type(4)));

#define LOG2E 1.4426950408889634f
__device__ __forceinline__ float fsig(float x) {
  return __builtin_amdgcn_rcpf(1.f + __builtin_amdgcn_exp2f(-LOG2E * x));
}
__device__ __forceinline__ float ftanh(float x) {
  return 2.f * __builtin_amdgcn_rcpf(
             1.f + __builtin_amdgcn_exp2f(-2.f * LOG2E * x)) - 1.f;
}
__device__ __forceinline__ u32 pkbf(float x, float y) {
  u32 a = __float_as_uint(x), b = __float_as_uint(y);
  a = (a + 0x7FFFu + ((a >> 16) & 1u)) >> 16;
  b = (b + 0x7FFFu + ((b >> 16) & 1u)) >> 16;
  return a | (b << 16);
}
__device__ __forceinline__ unsigned short f2bf(float x) {
  u32 a = __float_as_uint(x);
  return (unsigned short)((a + 0x7FFFu + ((a >> 16) & 1u)) >> 16);
}
#define MFMA __builtin_amdgcn_mfma_f32_16x16x32_bf16

// ---------------------------------------------------------------------------
// MFMA GEMM (K=128): C[M][N] = A[M][128] @ B[N][128]^T (+bias), A fp32 with
// on-the-fly bf16 pack, B pre-packed MFMA fragments, out fp32 or bf16.
// 256 threads = 4 waves; wave w owns rows bid*64+w*16..+16, loops N in
// 64-col chunks (16 B-frags + 16 MFMA per chunk).
// ---------------------------------------------------------------------------
__global__ __launch_bounds__(256) void gemm_mfma(
    const float* __restrict__ A, const u32* __restrict__ Bpk,
    const float* __restrict__ bias, void* __restrict__ Cout,
    int M, int N, int out_bf16) {
  int w = threadIdx.x >> 6, lane = threadIdx.x & 63;
  int R0 = blockIdx.x * 64 + w * 16;
  int r = R0 + (lane & 15);
  int rm = (r < M) ? r : (M - 1);
  const float* Ar = A + (size_t)rm * 128 + (lane >> 4) * 8;
  s16x8 a0, a1, a2, a3;
  {
#define LDA(AF, KT) { \
    float4 f0 = *(const float4*)(Ar + KT * 32); \
    float4 f1 = *(const float4*)(Ar + KT * 32 + 4); \
    u32x4v q = {pkbf(f0.x, f0.y), pkbf(f0.z, f0.w), \
                pkbf(f1.x, f1.y), pkbf(f1.z, f1.w)}; \
    AF = __builtin_bit_cast(s16x8, q); }
    LDA(a0, 0) LDA(a1, 1) LDA(a2, 2) LDA(a3, 3)
#undef LDA
  }
  const u32x4v* Bp = (const u32x4v*)Bpk;
  for (int c = 0; c < N; c += 64) {
    f32x4 acc0, acc1, acc2, acc3;
    {
      float b0 = bias ? bias[c + (lane & 15)]      : 0.f;
      float b1 = bias ? bias[c + 16 + (lane & 15)] : 0.f;
      float b2 = bias ? bias[c + 32 + (lane & 15)] : 0.f;
      float b3 = bias ? bias[c + 48 + (lane & 15)] : 0.f;
      acc0 = (f32x4){b0, b0, b0, b0}; acc1 = (f32x4){b1, b1, b1, b1};
      acc2 = (f32x4){b2, b2, b2, b2}; acc3 = (f32x4){b3, b3, b3, b3};
    }
    int fbase = (c >> 4) * 4;      // frag id = (c/16 + nt)*4 + kt
#define DONT(ACC, NT) { \
    s16x8 bf0 = __builtin_bit_cast(s16x8, Bp[(size_t)(fbase + NT * 4 + 0) * 64 + lane]); \
    s16x8 bf1 = __builtin_bit_cast(s16x8, Bp[(size_t)(fbase + NT * 4 + 1) * 64 + lane]); \
    s16x8 bf2 = __builtin_bit_cast(s16x8, Bp[(size_t)(fbase + NT * 4 + 2) * 64 + lane]); \
    s16x8 bf3 = __builtin_bit_cast(s16x8, Bp[(size_t)(fbase + NT * 4 + 3) * 64 + lane]); \
    ACC = MFMA(a0, bf0, ACC, 0, 0, 0); ACC = MFMA(a1, bf1, ACC, 0, 0, 0); \
    ACC = MFMA(a2, bf2, ACC, 0, 0, 0); ACC = MFMA(a3, bf3, ACC, 0, 0, 0); }
    DONT(acc0, 0) DONT(acc1, 1) DONT(acc2, 2) DONT(acc3, 3)
#undef DONT
    // store: D col = lane&15, row = (lane>>4)*4 + j
    int colb = c + (lane & 15);
    int rowb = R0 + (lane >> 4) * 4;
#define STNT(ACC, NT) \
    _Pragma("unroll") \
    for (int j = 0; j < 4; j++) { \
      int row = rowb + j; \
      if (row < M) { \
        if (out_bf16) ((unsigned short*)Cout)[(size_t)row * N + colb + NT * 16] = f2bf(ACC[j]); \
        else ((float*)Cout)[(size_t)row * N + colb + NT * 16] = ACC[j]; \
      } \
    }
    STNT(acc0, 0) STNT(acc1, 1) STNT(acc2, 2) STNT(acc3, 3)
#undef STNT
  }
}

// ---------------------------------------------------------------------------
// fp32 GEMM (kept for the K=192 xeL step): C = A @ B^T (+bias)
// ---------------------------------------------------------------------------
__global__ __launch_bounds__(256) void sgemm_nt(const float* __restrict__ A,
    const float* __restrict__ B, const float* __restrict__ bias,
    float* __restrict__ C, int M, int N, int K) {
  __shared__ float As[32][68];
  __shared__ float Bs[32][132];
  const int bm = blockIdx.y * 64, bn = blockIdx.x * 128;
  const int tid = threadIdx.x;
  const int tm = (tid >> 4) << 2;
  const int tn = (tid & 15) << 3;
  const int srow = tid >> 3;
  const int q4 = (tid & 7) << 2;

  float acc[4][8];
  #pragma unroll
  for (int i = 0; i < 4; i++)
    #pragma unroll
    for (int j = 0; j < 8; j++) acc[i][j] = 0.f;

  for (int k0 = 0; k0 < K; k0 += 32) {
    #pragma unroll
    for (int h = 0; h < 2; h++) {
      int gm = bm + srow + h * 32;
      int rm = (gm < M) ? gm : (M - 1);
      float4 av = *(const float4*)&A[(size_t)rm * K + k0 + q4];
      As[q4 + 0][srow + h * 32] = av.x;
      As[q4 + 1][srow + h * 32] = av.y;
      As[q4 + 2][srow + h * 32] = av.z;
      As[q4 + 3][srow + h * 32] = av.w;
    }
    #pragma unroll
    for (int h = 0; h < 4; h++) {
      int gn = bn + srow + h * 32;
      float4 bv = make_float4(0.f, 0.f, 0.f, 0.f);
      if (gn < N) bv = *(const float4*)&B[(size_t)gn * K + k0 + q4];
      Bs[q4 + 0][srow + h * 32] = bv.x;
      Bs[q4 + 1][srow + h * 32] = bv.y;
      Bs[q4 + 2][srow + h * 32] = bv.z;
      Bs[q4 + 3][srow + h * 32] = bv.w;
    }
    __syncthreads();
    #pragma unroll
    for (int kk = 0; kk < 32; kk++) {
      float4 a4 = *(const float4*)&As[kk][tm];
      float4 b0 = *(const float4*)&Bs[kk][tn];
      float4 b1 = *(const float4*)&Bs[kk][tn + 4];
      float a[4] = {a4.x, a4.y, a4.z, a4.w};
      float b[8] = {b0.x, b0.y, b0.z, b0.w, b1.x, b1.y, b1.z, b1.w};
      #pragma unroll
      for (int i = 0; i < 4; i++)
        #pragma unroll
        for (int j = 0; j < 8; j++) acc[i][j] += a[i] * b[j];
    }
    __syncthreads();
  }

  float bb[8];
  #pragma unroll
  for (int j = 0; j < 8; j++) {
    int gn = bn + tn + j;
    bb[j] = (bias && gn < N) ? bias[gn] : 0.f;
  }
  if (bn + tn < N) {
    #pragma unroll
    for (int i = 0; i < 4; i++) {
      int gm = bm + tm + i;
      if (gm >= M) continue;
      float4 v0 = make_float4(acc[i][0] + bb[0], acc[i][1] + bb[1],
                              acc[i][2] + bb[2], acc[i][3] + bb[3]);
      float4 v1 = make_float4(acc[i][4] + bb[4], acc[i][5] + bb[5],
                              acc[i][6] + bb[6], acc[i][7] + bb[7]);
      *(float4*)&C[(size_t)gm * N + bn + tn] = v0;
      *(float4*)&C[(size_t)gm * N + bn + tn + 4] = v1;
    }
  }
}

// ---------------------------------------------------------------------------
// Prep: ball = [bxF; bxB]; Wxp = lstm_Wx padded to K=192;
//       Wcpk  = Wc_w  MFMA B-frags (32 frags),
//       Wallpk= [WxF;WxB] MFMA B-frags (48 frags, N=192),
//       Wpk   = lstm_Wh MFMA B-frags (32 frags) for k_lstm.
// Frag layout: frag fg=nt*4+kt, lane l, pair p: n = nt*16+(l&15),
// k = kt*32 + (l>>4)*8 + 2p.
// ---------------------------------------------------------------------------
__global__ __launch_bounds__(256) void k_prep(const float* __restrict__ WxF,
    const float* __restrict__ WxB, const float* __restrict__ bxF,
    const float* __restrict__ bxB, const float* __restrict__ lstm_Wx,
    const float* __restrict__ lstm_Wh, const float* __restrict__ Wc_w,
    float* __restrict__ ball, float* __restrict__ Wxp,
    u32* __restrict__ Wcpk, u32* __restrict__ Wallpk, u32* __restrict__ Wpk) {
  int i = blockIdx.x * 256 + threadIdx.x;
  if (i < 96) ball[i] = bxF[i];
  else if (i < 192) ball[i] = bxB[i - 96];
  if (i < 8192) {   // Wcpk: 32 frags
    int fg = i >> 8, l = (i >> 2) & 63, p = i & 3;
    int nt = fg >> 2, kt = fg & 3;
    int n = nt * 16 + (l & 15);
    int k = kt * 32 + (l >> 4) * 8 + 2 * p;
    Wcpk[i] = pkbf(Wc_w[n * 128 + k], Wc_w[n * 128 + k + 1]);
  }
  if (i < 12288) {  // Wallpk: 48 frags (N=192)
    int fg = i >> 8, l = (i >> 2) & 63, p = i & 3;
    int nt = fg >> 2, kt = fg & 3;
    int n = nt * 16 + (l & 15);
    int k = kt * 32 + (l >> 4) * 8 + 2 * p;
    float v0 = (n < 96) ? WxF[n * 128 + k]     : WxB[(n - 96) * 128 + k];
    float v1 = (n < 96) ? WxF[n * 128 + k + 1] : WxB[(n - 96) * 128 + k + 1];
    Wallpk[i] = pkbf(v0, v1);
  }
  if (i < 32768) {  // Wpk (lstm): frag fg = w*16 + nt*4 + kt over N=512
    int fg = i >> 8, l = (i >> 2) & 63, p = i & 3;
    int w = fg >> 4, nt = (fg >> 2) & 3, kt = fg & 3;
    int n = 64 * w + 16 * nt + (l & 15);
    int k = 32 * kt + 8 * (l >> 4) + 2 * p;
    Wpk[i] = pkbf(lstm_Wh[n * 128 + k], lstm_Wh[n * 128 + k + 1]);
  }
  if (i < 512 * LIN_P) {
    int n = i / LIN_P, k = i - n * LIN_P;
    Wxp[i] = (k < LIN_D) ? lstm_Wx[n * LIN_D + k] : 0.f;
  }
}

// ---------------------------------------------------------------------------
// Tree: gather 15 bf16 rows of Ep, bottom-up subtree sums, node max with
// bias*subtree_count folded in. 2 trees per block. x out fp32.
// ---------------------------------------------------------------------------
__global__ __launch_bounds__(256) void k_tree(const int* __restrict__ ast,
    const u32* __restrict__ Epb, const float* __restrict__ Wc_b,
    float* __restrict__ x) {
  int lt = threadIdx.x >> 7;      // 0/1
  int d  = threadIdx.x & 127;
  int tree = blockIdx.x * 2 + lt;
  __shared__ int toks[2][15];
  if (d < 15) toks[lt][d] = ast[(size_t)tree * 15 + d];
  __syncthreads();
  float e[15];
  int half = d >> 1;
  bool odd = (d & 1) != 0;
  #pragma unroll
  for (int n = 0; n < 15; n++) {
    u32 v = Epb[(size_t)toks[lt][n] * 64 + half];
    e[n] = __uint_as_float(odd ? (v & 0xFFFF0000u) : (v << 16));
  }
  float b = Wc_b[d];
  float s3 = e[3] + e[7] + e[8],  s4 = e[4] + e[9] + e[10];
  float s5 = e[5] + e[11] + e[12], s6 = e[6] + e[13] + e[14];
  float s1 = e[1] + s3 + s4, s2 = e[2] + s5 + s6;
  float s0 = e[0] + s1 + s2;
  float ml = fmaxf(fmaxf(fmaxf(e[7], e[8]), fmaxf(e[9], e[10])),
                   fmaxf(fmaxf(e[11], e[12]), fmaxf(e[13], e[14]))) + b;
  float mm = fmaxf(fmaxf(s3, s4), fmaxf(s5, s6)) + 3.f * b;
  float mt = fmaxf(s1, s2) + 7.f * b;
  float m = fmaxf(fmaxf(ml, mm), fmaxf(mt, s0 + 15.f * b));
  x[(size_t)tree * 128 + d] = m;
}

// ---------------------------------------------------------------------------
// GRU recurrence, one block per (sequence, direction). Hidden=32, gates=96.
// ---------------------------------------------------------------------------
__global__ __launch_bounds__(128) void k_gru(const float* __restrict__ xe_all,
    const float* __restrict__ WhF, const float* __restrict__ WhB,
    const float* __restrict__ bhF, const float* __restrict__ bhB,
    float* __restrict__ code) {
  int bsq = blockIdx.x >> 1, dir = blockIdx.x & 1;
  int g = threadIdx.x;
  __shared__ float whs[96 * 32];
  __shared__ float h_lds[32];
  __shared__ float rz[64];
  __shared__ float nn[32];
  const float* Wh = dir ? WhB : WhF;
  const float* bh = dir ? bhB : bhF;
  for (int i = g; i < 96 * 32; i += 128) whs[i] = Wh[i];
  if (g < 32) h_lds[g] = 0.f;
  __syncthreads();
  float w[32]; float bhv = 0.f, mxv = -1e30f;
  if (g < 96) {
    #pragma unroll
    for (int j = 0; j < 32; j++) w[j] = whs[g * 32 + j];
    bhv = bh[g];
  }
  for (int s = 0; s < 16; s++) {
    int t = dir ? (15 - s) : s;
    const float* xe = xe_all + ((size_t)(bsq * 16 + t)) * 192 + dir * 96;
    float gh = bhv, xv = 0.f;
    if (g < 96) {
      xv = xe[g];
      #pragma unroll
      for (int j = 0; j < 32; j++) gh += w[j] * h_lds[j];
    }
    if (g < 64) rz[g] = fsig(xv + gh);
    __syncthreads();
    if (g >= 64 && g < 96) nn[g - 64] = ftanh(xv + rz[g - 64] * gh);
    __syncthreads();
    if (g < 32) {
      float z = rz[g + 32];
      float hn = (1.f - z) * nn[g] + z * h_lds[g];
      mxv = fmaxf(mxv, hn);
      h_lds[g] = hn;
    }
    __syncthreads();
  }
  if (g < 32) code[(size_t)bsq * 64 + dir * 32 + g] = mxv;
}

// ---------------------------------------------------------------------------
// Build lin = [c_embed(101) | code(64) | cur_result(2) | 0-pad to 192]
// ---------------------------------------------------------------------------
__global__ __launch_bounds__(256) void k_lin(const float* __restrict__ c_embed,
    const float* __restrict__ code, const float* __restrict__ cur,
    float* __restrict__ lin) {
  int i = blockIdx.x * 256 + threadIdx.x;
  if (i >= NROW * LIN_P) return;
  int row = i / LIN_P, j = i - row * LIN_P;
  float v;
  if (j < 101) v = c_embed[row * 101 + j];
  else if (j < 165) v = code[row * 64 + (j - 101)];
  else if (j < 167) v = cur[row * 2 + (j - 165)];
  else v = 0.f;
  lin[i] = v;
}

// ---------------------------------------------------------------------------
// LSTM v11 (MFMA, all-on-chip loop): 32 blocks x 512 threads, 1 block/CU.
// xe slice staged in LDS (100 KB), h history in LDS, weights as MFMA
// B-fragments in registers; loop touches only LDS.
// ---------------------------------------------------------------------------
__global__ __launch_bounds__(512) void k_lstm(
    const float* __restrict__ xeL, const u32* __restrict__ Wpk,
    const float* __restrict__ bh, float* __restrict__ lout) {
  __shared__ float xl[SEQ * 512];
  __shared__ float hh[SEQ * 128];
  __shared__ float ga[512];
  __shared__ s16x8 hl8[16];
  short* hls = (short*)hl8;
  int b = blockIdx.x, t = threadIdx.x;
  int w = t >> 6, lane = t & 63;
  const float* xrow = xeL + (size_t)b * SEQ * 512;
  #pragma unroll 5
  for (int i = t; i < SEQ * 512; i += 512) xl[i] = xrow[i];
  const s16x8* WB = (const s16x8*)Wpk + (size_t)w * 16 * 64 + lane;
  s16x8 B0  = WB[0 * 64],  B1  = WB[1 * 64],  B2  = WB[2 * 64],  B3  = WB[3 * 64];
  s16x8 B4  = WB[4 * 64],  B5  = WB[5 * 64],  B6  = WB[6 * 64],  B7  = WB[7 * 64];
  s16x8 B8  = WB[8 * 64],  B9  = WB[9 * 64],  B10 = WB[10 * 64], B11 = WB[11 * 64];
  s16x8 B12 = WB[12 * 64], B13 = WB[13 * 64], B14 = WB[14 * 64], B15 = WB[15 * 64];

  int gbase = 64 * w + lane;
  float bhv0 = 0, bhv1 = 0, bhv2 = 0, bhv3 = 0;
  if (lane < 16) {
    bhv0 = bh[gbase]; bhv1 = bh[gbase + 16];
    bhv2 = bh[gbase + 32]; bhv3 = bh[gbase + 48];
  }
  float c = 0.f;
  if (t < 128) hls[t] = 0;
  __syncthreads();
  const s16x8 zz = {0, 0, 0, 0, 0, 0, 0, 0};
  const bool arow = (lane & 15) == 0;
  const int asel = lane >> 4;
  const bool tanh_gate = (w == 4 || w == 5);
  for (int step = 0; step < SEQ; step++) {
    s16x8 a0 = arow ? hl8[asel]      : zz;
    s16x8 a1 = arow ? hl8[4 + asel]  : zz;
    s16x8 a2 = arow ? hl8[8 + asel]  : zz;
    s16x8 a3 = arow ? hl8[12 + asel] : zz;
    f32x4 acc0 = {0, 0, 0, 0}, acc1 = {0, 0, 0, 0};
    f32x4 acc2 = {0, 0, 0, 0}, acc3 = {0, 0, 0, 0};
    if (lane < 16) {
      const float* xs = xl + step * 512;
      acc0[0] = xs[gbase]      + bhv0;
      acc1[0] = xs[gbase + 16] + bhv1;
      acc2[0] = xs[gbase + 32] + bhv2;
      acc3[0] = xs[gbase + 48] + bhv3;
    }
    acc0 = MFMA(a0, B0,  acc0, 0, 0, 0); acc0 = MFMA(a1, B1,  acc0, 0, 0, 0);
    acc0 = MFMA(a2, B2,  acc0, 0, 0, 0); acc0 = MFMA(a3, B3,  acc0, 0, 0, 0);
    acc1 = MFMA(a0, B4,  acc1, 0, 0, 0); acc1 = MFMA(a1, B5,  acc1, 0, 0, 0);
    acc1 = MFMA(a2, B6,  acc1, 0, 0, 0); acc1 = MFMA(a3, B7,  acc1, 0, 0, 0);
    acc2 = MFMA(a0, B8,  acc2, 0, 0, 0); acc2 = MFMA(a1, B9,  acc2, 0, 0, 0);
    acc2 = MFMA(a2, B10, acc2, 0, 0, 0); acc2 = MFMA(a3, B11, acc2, 0, 0, 0);
    acc3 = MFMA(a0, B12, acc3, 0, 0, 0); acc3 = MFMA(a1, B13, acc3, 0, 0, 0);
    acc3 = MFMA(a2, B14, acc3, 0, 0, 0); acc3 = MFMA(a3, B15, acc3, 0, 0, 0);
    if (lane < 16) {
      if (tanh_gate) {
        ga[gbase]      = ftanh(acc0[0]);
        ga[gbase + 16] = ftanh(acc1[0]);
        ga[gbase + 32] = ftanh(acc2[0]);
        ga[gbase + 48] = ftanh(acc3[0]);
      } else {
        ga[gbase]      = fsig(acc0[0]);
        ga[gbase + 16] = fsig(acc1[0]);
        ga[gbase + 32] = fsig(acc2[0]);
        ga[gbase + 48] = fsig(acc3[0]);
      }
    }
    __syncthreads();
    if (t < 128) {
      c = ga[t + 128] * c + ga[t] * ga[t + 256];
      float h = ga[t + 384] * ftanh(c);
      hh[step * 128 + t] = h;
      u32 xb = __float_as_uint(h);
      hls[t] = (short)((xb + 0x7FFFu + ((xb >> 16) & 1u)) >> 16);
    }
    __syncthreads();
  }
  float* lo = lout + (size_t)b * SEQ * 128;
  #pragma unroll 4
  for (int i = t; i < SEQ * 128; i += 512) lo[i] = hh[i];
}

// ---------------------------------------------------------------------------
// Prediction head: p1 = lout . (pred_w^T tc) + tc . pred_b
// ---------------------------------------------------------------------------
__global__ __launch_bounds__(128) void k_pred(const float* __restrict__ lout,
    const float* __restrict__ pred_w, const float* __restrict__ pred_b,
    const float* __restrict__ tc, const float* __restrict__ result,
    float* __restrict__ out, float* __restrict__ fpbuf, float* __restrict__ mbuf) {
  int row = blockIdx.x; int k = threadIdx.x;
  __shared__ float tcs[101];
  __shared__ float r1[128], r2[128], r3[128];
  if (k < 101) tcs[k] = tc[(size_t)row * 101 + k];
  __syncthreads();
  float lk = lout[(size_t)row * 128 + k];
  float acc = 0.f;
  for (int c = 0; c < 101; c++) acc += tcs[c] * pred_w[c * 128 + k];
  float v = acc * lk;
  float pb = (k < 101) ? tcs[k] * pred_b[k] : 0.f;
  float nc = (k < 101) ? tcs[k] : 0.f;
  r1[k] = v; r2[k] = pb; r3[k] = nc;
  __syncthreads();
  for (int st = 64; st > 0; st >>= 1) {
    if (k < st) { r1[k] += r1[k + st]; r2[k] += r2[k + st]; r3[k] += r3[k + st]; }
    __syncthreads();
  }
  if (k == 0) {
    float ncon = r3[0];
    float m = (ncon > 0.f) ? 1.f : 0.f;
    float fp = (r1[0] + r2[0]) / fmaxf(ncon, 1.f);
    fpbuf[row] = fp; mbuf[row] = m;
    out[1 + row] = m / (1.f + expf(-fp));
    out[1 + NROW + row] = result[row] * m;
  }
}

// ---------------------------------------------------------------------------
// Loss reduction (single block, deterministic tree reduce)
// ---------------------------------------------------------------------------
__global__ __launch_bounds__(256) void k_loss(const float* __restrict__ fpbuf,
    const float* __restrict__ mbuf, const float* __restrict__ result,
    float* __restrict__ out) {
  __shared__ float sb[256], sm[256];
  int k = threadIdx.x;
  float ab = 0.f, am = 0.f;
  for (int r = k; r < NROW; r += 256) {
    float fp = fpbuf[r], m = mbuf[r], res = result[r];
    float bce = fmaxf(fp, 0.f) - fp * res + log1pf(expf(-fabsf(fp)));
    ab += bce * m; am += m;
  }
  sb[k] = ab; sm[k] = am;
  __syncthreads();
  for (int st = 128; st > 0; st >>= 1) {
    if (k < st) { sb[k] += sb[k + st]; sm[k] += sm[k + st]; }
    __syncthreads();
  }
  if (k == 0) out[0] = sb[0] / fmaxf(sm[0], 1.f);
}

// ---------------------------------------------------------------------------
extern "C" void kernel_launch(void* const* d_in, const int* in_sizes, int n_in,
                              void* d_out, int out_size, void* d_ws, size_t ws_size,
                              hipStream_t stream) {
  (void)in_sizes; (void)n_in; (void)out_size; (void)ws_size;
  const int*   ast      = (const int*)  d_in[2];
  const float* target_c = (const float*)d_in[3];
  const float* c_embed  = (const float*)d_in[4];
  const float* cur_res  = (const float*)d_in[5];
  const float* result   = (const float*)d_in[6];
  const float* emb      = (const float*)d_in[7];
  const float* Wc_w     = (const float*)d_in[8];
  const float* Wc_b     = (const float*)d_in[9];
  const float* gru_WxF  = (const float*)d_in[10];
  const float* gru_WhF  = (const float*)d_in[11];
  const float* gru_bxF  = (const float*)d_in[12];
  const float* gru_bhF  = (const float*)d_in[13];
  const float* gru_WxB  = (const float*)d_in[14];
  const float* gru_WhB  = (const float*)d_in[15];
  const float* gru_bxB  = (const float*)d_in[16];
  const float* gru_bhB  = (const float*)d_in[17];
  const float* lstm_Wx  = (const float*)d_in[18];
  const float* lstm_Wh  = (const float*)d_in[19];
  const float* lstm_bx  = (const float*)d_in[20];
  const float* lstm_bh  = (const float*)d_in[21];
  const float* pred_w   = (const float*)d_in[22];
  const float* pred_b   = (const float*)d_in[23];
  float* out = (float*)d_out;

  float* W = (float*)d_ws;
  u32*   Epb    = (u32*)W;               // 3,200,000 f-equiv (50000x128 bf16)
  float* x      = W + 3200000;           // 3,276,800
  float* xe_all = W + 6476800;           // 4,915,200
  u32*   Wcpk   = (u32*)(W + 11392000);  // 8,192
  u32*   Wallpk = (u32*)(W + 11400192);  // 12,288
  float* ball   = W + 11412480;          // 192
  float* Wxp    = W + 11412672;          // 98,304
  float* code   = W + 11510976;          // 102,400
  float* lin    = W + 11613376;          // 307,200
  float* xeL    = W + 11920576;          // 819,200
  float* lout   = W + 12739776;          // 204,800
  float* fpbuf  = W + 12944576;          // 1,600
  float* mbuf   = W + 12946176;          // 1,600
  u32*   Wpk    = (u32*)(W + 12947776);  // 32,768

  // 1. weight prep (frag packs + Wx pad)
  k_prep<<<384, 256, 0, stream>>>(gru_WxF, gru_WxB, gru_bxF, gru_bxB, lstm_Wx,
                                  lstm_Wh, Wc_w, ball, Wxp, Wcpk, Wallpk, Wpk);
  // 2. Ep = emb @ Wc_w^T (MFMA, bf16 out)
  gemm_mfma<<<782, 256, 0, stream>>>(emb, Wcpk, nullptr, Epb, VOCAB, 128, 1);
  // 3. tree gather/sum/max -> x (25600 x 128, bf16 gather)
  k_tree<<<NTREE / 2, 256, 0, stream>>>(ast, Epb, Wc_b, x);
  // 4. xe_all = x @ Wall^T + ball (MFMA, fp32 out, N=192)
  gemm_mfma<<<400, 256, 0, stream>>>(x, Wallpk, ball, xe_all, NTREE, 192, 0);
  // 5. GRU recurrence + time max -> code (1600 x 64)
  k_gru<<<NROW * 2, 128, 0, stream>>>(xe_all, gru_WhF, gru_WhB, gru_bhF, gru_bhB, code);
  // 6. lin build (1600 x 192, zero-padded)
  k_lin<<<(NROW * LIN_P + 255) / 256, 256, 0, stream>>>(c_embed, code, cur_res, lin);
  // 7. xeL = lin @ Wxp^T + lstm_bx (1600 x 512, K=192)
  sgemm_nt<<<dim3(4, 25), 256, 0, stream>>>(lin, Wxp, lstm_bx, xeL, NROW, 512, LIN_P);
  // 8. LSTM recurrence -> lout (1600 x 128)  [MFMA, all-on-chip loop]
  k_lstm<<<BS, 512, 0, stream>>>(xeL, Wpk, lstm_bh, lout);
  // 9. prediction head -> out[1..], fpbuf, mbuf
  k_pred<<<NROW, 128, 0, stream>>>(lout, pred_w, pred_b, target_c, result,
                                   out, fpbuf, mbuf);
  // 10. loss -> out[0]
  k_loss<<<1, 256, 0, stream>>>(fpbuf, mbuf, result, out);
}